// Round 10
// baseline (241.613 us; speedup 1.0000x reference)
//
#include <hip/hip_runtime.h>
#include <hip/hip_bf16.h>

#define B_ 2
#define T_ 2048
#define C_ 2048
#define H_ 16
#define KH_ 4
#define D_ 128

typedef unsigned short ushort_t;
typedef __attribute__((ext_vector_type(8))) short short8;
typedef __attribute__((ext_vector_type(4))) float f32x4;

#define RSQRT_D 0.08838834764831845f
#define L2E 1.4426950408889634f
// Q pre-scale: 1/sqrt(D) * log2(e)  ->  QK^T lands in log2 units, softmax is pure exp2
#define QSCALE (0.08838834764831845f * 1.4426950408889634f)

__device__ __forceinline__ ushort_t f2b(float f) {
  union { float f; unsigned u; } v; v.f = f;
  unsigned r = v.u + 0x7fffu + ((v.u >> 16) & 1u);
  return (ushort_t)(r >> 16);
}
__device__ __forceinline__ float b2f(ushort_t u) {
  union { unsigned u; float f; } v; v.u = ((unsigned)u) << 16;
  return v.f;
}

__device__ __forceinline__ f32x4 mfma16(short8 a, short8 b, f32x4 c) {
  return __builtin_amdgcn_mfma_f32_16x16x32_bf16(a, b, c, 0, 0, 0);
}

__device__ __forceinline__ void async16(const void* g, void* l) {
  __builtin_amdgcn_global_load_lds(
      (const __attribute__((address_space(1))) void*)g,
      (__attribute__((address_space(3))) void*)l, 16, 0, 0);
}

// packed f32x2 -> bf16x2 (RTNE); dst.lo = bf16(lo), dst.hi = bf16(hi)
__device__ __forceinline__ unsigned cvtpk(float lo, float hi) {
  unsigned r;
  asm volatile("v_cvt_pk_bf16_f32 %0, %1, %2" : "=v"(r) : "v"(lo), "v"(hi));
  return r;
}

// ---------------- small prep kernels ----------------

__global__ void convert_f32_bf16(const float* __restrict__ in, ushort_t* __restrict__ out, int n4) {
  int i = blockIdx.x * blockDim.x + threadIdx.x;
  if (i >= n4) return;
  float4 v = ((const float4*)in)[i];
  ushort4 o;
  o.x = f2b(v.x); o.y = f2b(v.y); o.z = f2b(v.z); o.w = f2b(v.w);
  ((ushort4*)out)[i] = o;
}

// out[c][r] = bf16(in[r][c]);  in: R x C f32, out: C x R bf16
__global__ void transpose_to_bf16(const float* __restrict__ in, ushort_t* __restrict__ out, int R, int C) {
  __shared__ float tile[32][33];
  int c0 = blockIdx.x * 32, r0 = blockIdx.y * 32;
  int tx = threadIdx.x, ty = threadIdx.y;
#pragma unroll
  for (int i = 0; i < 4; i++) {
    int r = ty + i * 8;
    tile[r][tx] = in[(size_t)(r0 + r) * C + c0 + tx];
  }
  __syncthreads();
#pragma unroll
  for (int i = 0; i < 4; i++) {
    int r = ty + i * 8;
    out[(size_t)(c0 + r) * R + r0 + tx] = f2b(tile[tx][r]);
  }
}

// cos/sin table: tab[t*64+d] = (cos(t*omega[d]), sin(t*omega[d]))
__global__ void rope_tab_k(const float* __restrict__ omega, float2* __restrict__ tab) {
  int idx = blockIdx.x * blockDim.x + threadIdx.x;  // 2048*64
  int d = idx & 63;
  int t = idx >> 6;
  float ang = (float)t * omega[d];
  tab[idx] = make_float2(cosf(ang), sinf(ang));
}

// QKVraw [b*T+t][3072]: cols 0..2047 = q -> rope (pre-scaled by QSCALE) -> Qb [(b*16+h)*T + t][d]
__global__ void rope_q_k(const ushort_t* __restrict__ QKVraw, const float2* __restrict__ tab,
                         ushort_t* __restrict__ Qb) {
  int idx = blockIdx.x * blockDim.x + threadIdx.x;  // B*T*H*64 = 4194304
  int d = idx & 63;
  int h = (idx >> 6) & 15;
  int t = (idx >> 10) & 2047;
  int b = idx >> 21;
  size_t in_off = (size_t)(b * 2048 + t) * 3072 + h * 128 + d;
  float x1 = b2f(QKVraw[in_off]);
  float x2 = b2f(QKVraw[in_off + 64]);
  float2 cs = tab[t * 64 + d];
  size_t out_off = ((size_t)(b * 16 + h) * 2048 + t) * 128 + d;
  Qb[out_off] = f2b((x1 * cs.x - x2 * cs.y) * QSCALE);
  Qb[out_off + 64] = f2b((x1 * cs.y + x2 * cs.x) * QSCALE);
}

// QKVraw cols 2048..2559 = k -> rope -> Kb [(b*4+kh)*T + t][d]
__global__ void rope_k_k(const ushort_t* __restrict__ QKVraw, const float2* __restrict__ tab,
                         ushort_t* __restrict__ Kb) {
  int idx = blockIdx.x * blockDim.x + threadIdx.x;  // B*T*KH*64 = 1048576
  int d = idx & 63;
  int kh = (idx >> 6) & 3;
  int t = (idx >> 8) & 2047;
  int b = idx >> 19;
  size_t in_off = (size_t)(b * 2048 + t) * 3072 + 2048 + kh * 128 + d;
  float x1 = b2f(QKVraw[in_off]);
  float x2 = b2f(QKVraw[in_off + 64]);
  float2 cs = tab[t * 64 + d];
  size_t out_off = ((size_t)(b * 4 + kh) * 2048 + t) * 128 + d;
  Kb[out_off] = f2b(x1 * cs.x - x2 * cs.y);
  Kb[out_off + 64] = f2b(x1 * cs.y + x2 * cs.x);
}

// V fragment pre-pack: Vf short8 index = (((z*32+tile)*2+hv)*8+n)*64 + lane
// element j = V[b][t = tile*64 + kl][kh][d = n*16 + (lane&15)]
// kl = (hv*2 + ((j>>1)>>1))*16 + (lane>>4)*4 + 2*((j>>1)&1) + (j&1)
__global__ void v_frag_k(const ushort_t* __restrict__ QKVraw, ushort_t* __restrict__ Vf) {
  int idx = blockIdx.x * blockDim.x + threadIdx.x;  // 262144 short8 units
  int lane = idx & 63;
  int n = (idx >> 6) & 7;
  int hv = (idx >> 9) & 1;
  int tile = (idx >> 10) & 31;
  int z = idx >> 15;  // b*4+kh
  int b = z >> 2, kh = z & 3;
  int lr = lane & 15, lc = lane >> 4;
  int d = n * 16 + lr;
  union { ushort_t u[8]; short8 v; } out;
#pragma unroll
  for (int j = 0; j < 8; j++) {
    int tw = j >> 1, par = j & 1;
    int kl = (hv * 2 + (tw >> 1)) * 16 + lc * 4 + 2 * (tw & 1) + par;
    int t = tile * 64 + kl;
    out.u[j] = QKVraw[(size_t)(b * 2048 + t) * 3072 + 2560 + kh * 128 + d];
  }
  *(short8*)(Vf + (size_t)idx * 8) = out.v;
}

// ---------------- GEMM: C[M][N] = A[M][K] @ Bt[N][K]^T  (bf16 in, f32 acc) ----------------
// 2-phase dbuf with COUNTED vmcnt (T4): raw s_barrier, vmcnt(4) keeps the 4
// prefetch loads in flight across the MFMA phase; vmcnt(0) only on the peeled
// last tile. FIFO vmcnt semantics guarantee tile-t's 4 loads are done.

__device__ __forceinline__ void store_out(float* C, size_t idx, float v) { C[idx] = v; }
__device__ __forceinline__ void store_out(ushort_t* C, size_t idx, float v) { C[idx] = f2b(v); }

template <typename OUT_T>
__global__ __launch_bounds__(256) void gemm_bt(const ushort_t* __restrict__ A,
                                               const ushort_t* __restrict__ Bt,
                                               OUT_T* __restrict__ C,
                                               int M, int N, int K) {
  __shared__ __attribute__((aligned(16))) ushort_t As[2][128 * 32];
  __shared__ __attribute__((aligned(16))) ushort_t Bs[2][128 * 32];
  const int tid = threadIdx.x;
  const int lane = tid & 63;
  const int w = tid >> 6;
  const int bm = blockIdx.y, bn = blockIdx.x;
  const int lr = lane & 15, lc = lane >> 4;
  const int wr = (w >> 1) * 64, wc = (w & 1) * 64;
  const ushort_t* Ab = A + (size_t)bm * 128 * K;
  const ushort_t* Bb = Bt + (size_t)bn * 128 * K;
  const int srow = tid >> 2;
  const int scol = (tid & 3) * 8;
  f32x4 acc[4][4];
#pragma unroll
  for (int i = 0; i < 4; i++)
#pragma unroll
    for (int j = 0; j < 4; j++) acc[i][j] = (f32x4)(0.0f);

  // prologue: stage tile 0 into buf 0 (4 vmem ops per wave)
  async16(Ab + (size_t)srow * K + scol, &As[0][0] + srow * 32 + scol);
  async16(Ab + (size_t)(srow + 64) * K + scol, &As[0][0] + (srow + 64) * 32 + scol);
  async16(Bb + (size_t)srow * K + scol, &Bs[0][0] + srow * 32 + scol);
  async16(Bb + (size_t)(srow + 64) * K + scol, &Bs[0][0] + (srow + 64) * 32 + scol);

  const int nt = K >> 5;
#pragma unroll 2
  for (int t = 0; t < nt - 1; t++) {
    const int cur = t & 1;
    // issue prefetch of tile t+1 into the other buffer (4 vmem ops)
    {
      const int k1 = (t + 1) << 5;
      ushort_t* Ad = &As[cur ^ 1][0];
      ushort_t* Bd = &Bs[cur ^ 1][0];
      async16(Ab + (size_t)srow * K + k1 + scol, Ad + srow * 32 + scol);
      async16(Ab + (size_t)(srow + 64) * K + k1 + scol, Ad + (srow + 64) * 32 + scol);
      async16(Bb + (size_t)srow * K + k1 + scol, Bd + srow * 32 + scol);
      async16(Bb + (size_t)(srow + 64) * K + k1 + scol, Bd + (srow + 64) * 32 + scol);
    }
    // wait tile t's 4 loads (oldest); let t+1's 4 stay in flight
    asm volatile("s_waitcnt vmcnt(4)" ::: "memory");
    __builtin_amdgcn_s_barrier();
    __builtin_amdgcn_sched_barrier(0);
    const ushort_t* Al = &As[cur][0];
    const ushort_t* Bl = &Bs[cur][0];
    short8 af[4], bf[4];
#pragma unroll
    for (int mi = 0; mi < 4; mi++)
      af[mi] = *(const short8*)(Al + (wr + mi * 16 + lr) * 32 + lc * 8);
#pragma unroll
    for (int ni = 0; ni < 4; ni++)
      bf[ni] = *(const short8*)(Bl + (wc + ni * 16 + lr) * 32 + lc * 8);
#pragma unroll
    for (int mi = 0; mi < 4; mi++)
#pragma unroll
      for (int ni = 0; ni < 4; ni++)
        acc[mi][ni] = mfma16(af[mi], bf[ni], acc[mi][ni]);
    asm volatile("" ::: "memory");
    __builtin_amdgcn_s_barrier();  // all waves done reading buf[cur] before t+2 overwrites
    asm volatile("" ::: "memory");
  }
  // peeled last tile: drain, then compute
  {
    const int cur = (nt - 1) & 1;
    asm volatile("s_waitcnt vmcnt(0)" ::: "memory");
    __builtin_amdgcn_s_barrier();
    __builtin_amdgcn_sched_barrier(0);
    const ushort_t* Al = &As[cur][0];
    const ushort_t* Bl = &Bs[cur][0];
    short8 af[4], bf[4];
#pragma unroll
    for (int mi = 0; mi < 4; mi++)
      af[mi] = *(const short8*)(Al + (wr + mi * 16 + lr) * 32 + lc * 8);
#pragma unroll
    for (int ni = 0; ni < 4; ni++)
      bf[ni] = *(const short8*)(Bl + (wc + ni * 16 + lr) * 32 + lc * 8);
#pragma unroll
    for (int mi = 0; mi < 4; mi++)
#pragma unroll
      for (int ni = 0; ni < 4; ni++)
        acc[mi][ni] = mfma16(af[mi], bf[ni], acc[mi][ni]);
  }
#pragma unroll
  for (int mi = 0; mi < 4; mi++) {
#pragma unroll
    for (int ni = 0; ni < 4; ni++) {
      int row = bm * 128 + wr + mi * 16 + lc * 4;
      int col = bn * 128 + wc + ni * 16 + lr;
#pragma unroll
      for (int r = 0; r < 4; r++)
        store_out(C, (size_t)(row + r) * N + col, acc[mi][ni][r]);
    }
  }
}

// ---------------- flash attention (causal GQA) ----------------
// QBLK=128, 4 waves x 32 q-rows (two 16-row frags). SPLIT-KV for heavy chunks:
// chunk s has 2s+2 kv-tiles; s>=8 is split into half0 = tiles [0,s+1) and
// half1 = [s+1,2s+2) handled by separate blocks writing UNNORMALIZED partials
// (bf16 O + f32 m,l) merged by merge_k. Max block weight 16 tiles (was 32 --
// the R8/R9 makespan limiter: the heavy block ran alone at 4 waves/CU).
// 24 weight-sorted items per (h,b) -> 768 blocks = 3/CU.
// Swapped QK^T (mfma(K,Q)); Q pre-scaled by QSCALE; defer-max thr 8 (P<=2^8).
static __device__ const signed char c_s[24] = {15,15,7,14,14,13,13,6,12,12,11,11,5,10,10,9,9,4,8,8,3,2,1,0};
static __device__ const signed char c_h[24] = {0,1,-1,0,1,0,1,-1,0,1,0,1,-1,0,1,0,1,-1,0,1,-1,-1,-1,-1};

__global__ __launch_bounds__(256, 2) void attn_k(const ushort_t* __restrict__ Qb,
                                                 const ushort_t* __restrict__ Kb,
                                                 const ushort_t* __restrict__ Vf,
                                                 ushort_t* __restrict__ Yb,
                                                 ushort_t* __restrict__ Po,
                                                 float* __restrict__ Pstat) {
  __shared__ __attribute__((aligned(16))) ushort_t Ks[2][64 * 128];  // 32 KB
  const int tid = threadIdx.x;
  const int lane = tid & 63;
  const int w = tid >> 6;
  const int lr = lane & 15, lc = lane >> 4;
  const int h = blockIdx.y;
  const int b = blockIdx.z;
  const int kh = h >> 2;
  const int item = blockIdx.x;          // 0..23, weight-descending
  const int s = c_s[item];
  const int hf = c_h[item];             // -1 unsplit, 0/1 = kv half
  const int t0 = (hf == 1) ? (s + 1) : 0;
  const int t1 = (hf == 0) ? (s + 1) : (2 * s + 2);
  const int q0w = s * 128 + w * 32;

  const ushort_t* Qp = Qb + (size_t)(b * 16 + h) * T_ * D_;
  const ushort_t* Kp = Kb + (size_t)(b * 4 + kh) * T_ * D_;
  const ushort_t* Vfb = Vf + (size_t)(b * 4 + kh) * 262144;

  const int st_row = tid >> 4;   // 0..15, +i*16
  const int st_slot = tid & 15;

  short8 qf[2][4];
#pragma unroll
  for (int f = 0; f < 2; f++)
#pragma unroll
    for (int c = 0; c < 4; c++)
      qf[f][c] = *(const short8*)(Qp + (size_t)(q0w + f * 16 + lr) * D_ + c * 32 + lc * 8);

  f32x4 o[2][8];
#pragma unroll
  for (int f = 0; f < 2; f++)
#pragma unroll
    for (int n = 0; n < 8; n++) o[f][n] = (f32x4)(0.0f);
  float m[2] = {-1e30f, -1e30f}, l[2] = {0.0f, 0.0f};

  // stage tile t0 into buffer (t0&1)
#pragma unroll
  for (int i = 0; i < 4; i++) {
    int row = i * 16 + st_row;
    async16(Kp + (size_t)(t0 * 64 + row) * D_ + (((st_slot - row) & 15) * 8),
            &Ks[t0 & 1][0] + row * 128 + st_slot * 8);
  }

#pragma unroll 1
  for (int ti = t0; ti < t1; ti++) {
    __syncthreads();  // K[ti] resident (vmcnt drained); buffers safe
    const int kv0 = ti * 64;
    if (ti + 1 < t1) {
      const ushort_t* Kn = Kp + (size_t)(kv0 + 64) * D_;
      ushort_t* dst = &Ks[(ti + 1) & 1][0];
#pragma unroll
      for (int i = 0; i < 4; i++) {
        int row = i * 16 + st_row;
        async16(Kn + (size_t)row * D_ + (((st_slot - row) & 15) * 8),
                dst + row * 128 + st_slot * 8);
      }
    }
    if (kv0 > q0w + 31) continue;  // wave fully masked (only last tile, waves 0-1)
    const ushort_t* Kl = &Ks[ti & 1][0];
    // V half 0 — early issue, hidden under QK
    const ushort_t* Vt0 = Vfb + (size_t)(ti * 2) * 4096;
    short8 vr0[8];
#pragma unroll
    for (int n = 0; n < 8; n++)
      vr0[n] = *(const short8*)(Vt0 + n * 512 + lane * 8);
    // QK^T swapped, both fragments off the SAME kf reads
    f32x4 s_[2][4];
#pragma unroll
    for (int f = 0; f < 2; f++)
#pragma unroll
      for (int kj = 0; kj < 4; kj++) s_[f][kj] = (f32x4)(0.0f);
    __builtin_amdgcn_s_setprio(1);
#pragma unroll
    for (int c = 0; c < 4; c++) {
      short8 kf[4];
#pragma unroll
      for (int kj = 0; kj < 4; kj++)
        kf[kj] = *(const short8*)(Kl + (kj * 16 + lr) * 128 + (((c * 4 + lc + lr) & 15) * 8));
#pragma unroll
      for (int f = 0; f < 2; f++)
#pragma unroll
        for (int kj = 0; kj < 4; kj++)
          s_[f][kj] = mfma16(kf[kj], qf[f][c], s_[f][kj]);
    }
    __builtin_amdgcn_s_setprio(0);
    // V half 1 — hidden under softmax
    const ushort_t* Vt1 = Vfb + (size_t)(ti * 2 + 1) * 4096;
    short8 vr1[8];
#pragma unroll
    for (int n = 0; n < 8; n++)
      vr1[n] = *(const short8*)(Vt1 + n * 512 + lane * 8);
    // softmax per fragment (lane's row q = q0w + f*16 + lr), log2 units
    const bool maskt = (kv0 + 63 > q0w);
    union { unsigned u[4]; short8 v; } pa0[2], pa1[2];
#pragma unroll
    for (int f = 0; f < 2; f++) {
      const int q = q0w + f * 16 + lr;
      float pv[16];
      float mx = -1e30f;
      if (maskt) {
#pragma unroll
        for (int kj = 0; kj < 4; kj++)
#pragma unroll
          for (int r = 0; r < 4; r++) {
            float a = s_[f][kj][r];
            if (kv0 + kj * 16 + lc * 4 + r > q) a = -1e30f;
            pv[kj * 4 + r] = a;
            mx = fmaxf(mx, a);
          }
      } else {
#pragma unroll
        for (int kj = 0; kj < 4; kj++)
#pragma unroll
          for (int r = 0; r < 4; r++) {
            float a = s_[f][kj][r];
            pv[kj * 4 + r] = a;
            mx = fmaxf(mx, a);
          }
      }
      mx = fmaxf(mx, __shfl_xor(mx, 16));
      mx = fmaxf(mx, __shfl_xor(mx, 32));
      // defer-max: rescale only when some row grew > 8 (log2) => P <= 2^8
      const bool need = __any(mx > m[f] + 8.0f);
      const float mn = need ? fmaxf(m[f], mx) : m[f];
      float rs = 0.0f;
#pragma unroll
      for (int i = 0; i < 16; i++) {
        pv[i] = exp2f(pv[i] - mn);
        rs += pv[i];
      }
      rs += __shfl_xor(rs, 16);
      rs += __shfl_xor(rs, 32);
      // pack P to bf16 A-frags (in-lane; layout matches Vf's sigma)
#pragma unroll
      for (int kj = 0; kj < 2; kj++) {
        pa0[f].u[kj * 2] = cvtpk(pv[kj * 4], pv[kj * 4 + 1]);
        pa0[f].u[kj * 2 + 1] = cvtpk(pv[kj * 4 + 2], pv[kj * 4 + 3]);
        pa1[f].u[kj * 2] = cvtpk(pv[8 + kj * 4], pv[8 + kj * 4 + 1]);
        pa1[f].u[kj * 2 + 1] = cvtpk(pv[8 + kj * 4 + 2], pv[8 + kj * 4 + 3]);
      }
      if (need) {
        float al = exp2f(m[f] - mn);
        m[f] = mn;
        l[f] = l[f] * al + rs;
        float alT[4];
#pragma unroll
        for (int r = 0; r < 4; r++)
          alT[r] = __shfl(al, (lane & 48) | (lc * 4 + r));
#pragma unroll
        for (int n = 0; n < 8; n++)
#pragma unroll
          for (int r = 0; r < 4; r++) o[f][n][r] *= alT[r];
      } else {
        l[f] += rs;
      }
    }
    __builtin_amdgcn_s_setprio(1);
#pragma unroll
    for (int n = 0; n < 8; n++) {
      o[0][n] = mfma16(pa0[0].v, vr0[n], o[0][n]);
      o[1][n] = mfma16(pa0[1].v, vr0[n], o[1][n]);
    }
#pragma unroll
    for (int n = 0; n < 8; n++) {
      o[0][n] = mfma16(pa1[0].v, vr1[n], o[0][n]);
      o[1][n] = mfma16(pa1[1].v, vr1[n], o[1][n]);
    }
    __builtin_amdgcn_s_setprio(0);
  }

  if (hf < 0) {
    // unsplit: normalize and write Yb directly
#pragma unroll
    for (int f = 0; f < 2; f++) {
      float inv = 1.0f / l[f];
      float invT[4];
#pragma unroll
      for (int r = 0; r < 4; r++)
        invT[r] = __shfl(inv, (lane & 48) | (lc * 4 + r));
#pragma unroll
      for (int n = 0; n < 8; n++)
#pragma unroll
        for (int r = 0; r < 4; r++) {
          int qo = q0w + f * 16 + lc * 4 + r;
          int d = n * 16 + lr;
          Yb[(size_t)(b * T_ + qo) * 2048 + h * 128 + d] = f2b(o[f][n][r] * invT[r]);
        }
    }
  } else {
    // split half: write unnormalized bf16 partial + f32 (m,l) stats
    const int pidx = ((b * 16 + h) * 8 + (s - 8)) * 2 + hf;
    ushort_t* Op = Po + (size_t)pidx * 16384;
    float* St = Pstat + (size_t)pidx * 256;
#pragma unroll
    for (int f = 0; f < 2; f++) {
#pragma unroll
      for (int n = 0; n < 8; n++)
#pragma unroll
        for (int r = 0; r < 4; r++) {
          int ql = w * 32 + f * 16 + lc * 4 + r;
          Op[ql * 128 + n * 16 + lr] = f2b(o[f][n][r]);
        }
      if (lc == 0) {
        St[w * 32 + f * 16 + lr] = m[f];
        St[128 + w * 32 + f * 16 + lr] = l[f];
      }
    }
  }
}

// merge two KV-half partials: O = (O1*2^(m1-M) + O2*2^(m2-M)) / L
// one 256-thread block per split chunk instance (256 total)
__global__ void merge_k(const ushort_t* __restrict__ Po, const float* __restrict__ Pstat,
                        ushort_t* __restrict__ Yb) {
  const int inst = blockIdx.x;          // = (b*16+h)*8 + (s-8)
  const int si = inst & 7;
  const int h = (inst >> 3) & 15;
  const int b = inst >> 7;
  const int s = 8 + si;
  const int p0 = inst * 2, p1 = p0 + 1;
  const int row = threadIdx.x >> 1;
  const int c0 = (threadIdx.x & 1) * 64;
  const float m1 = Pstat[p0 * 256 + row], l1 = Pstat[p0 * 256 + 128 + row];
  const float m2 = Pstat[p1 * 256 + row], l2 = Pstat[p1 * 256 + 128 + row];
  const float M = fmaxf(m1, m2);
  const float w1 = exp2f(m1 - M), w2 = exp2f(m2 - M);
  const float inv = 1.0f / (l1 * w1 + l2 * w2);
  const ushort_t* O1 = Po + (size_t)p0 * 16384 + row * 128 + c0;
  const ushort_t* O2 = Po + (size_t)p1 * 16384 + row * 128 + c0;
  ushort_t* Y = Yb + (size_t)(b * T_ + s * 128 + row) * 2048 + h * 128 + c0;
#pragma unroll
  for (int j8 = 0; j8 < 8; j8++) {
    union { ushort_t u[8]; short8 v; } a, bb, r;
    a.v = *(const short8*)(O1 + j8 * 8);
    bb.v = *(const short8*)(O2 + j8 * 8);
#pragma unroll
    for (int e = 0; e < 8; e++)
      r.u[e] = f2b((b2f(a.u[e]) * w1 + b2f(bb.u[e]) * w2) * inv);
    *(short8*)(Y + j8 * 8) = r.v;
  }
}

// ---------------- launch ----------------

extern "C" void kernel_launch(void* const* d_in, const int* in_sizes, int n_in,
                              void* d_out, int out_size, void* d_ws, size_t ws_size,
                              hipStream_t stream) {
  (void)in_sizes; (void)n_in; (void)out_size; (void)ws_size;
  const float* x = (const float*)d_in[0];
  const float* wq = (const float*)d_in[1];
  const float* wkv = (const float*)d_in[2];
  const float* wproj = (const float*)d_in[3];
  const float* omega = (const float*)d_in[4];
  float* out = (float*)d_out;
  char* ws = (char*)d_ws;

  ushort_t* xb     = (ushort_t*)(ws + 0);          // 4096x2048 bf16 = 16.8MB (dead after QKV GEMM)
  ushort_t* wqkvT  = (ushort_t*)(ws + 16777216);   // [3072][2048] bf16 (dead after QKV GEMM)
  ushort_t* wkvT   = (ushort_t*)(ws + 25165824);   // tail of wqkvT
  ushort_t* wprojT = (ushort_t*)(ws + 29360128);   // 2048x2048 bf16
  ushort_t* QKVraw = (ushort_t*)(ws + 37748736);   // 4096x3072 bf16 = 25.2MB
  ushort_t* Qb     = (ushort_t*)(ws + 62914560);   // [b][h][t][d] bf16
  ushort_t* Kb     = (ushort_t*)(ws + 79691776);   // [b][kh][t][d] bf16
  ushort_t* Vf     = (ushort_t*)(ws + 83886080);   // V fragment-packed, 4MB
  ushort_t* Yb     = (ushort_t*)(ws + 88080384);   // 4096x2048 bf16
  float2*   tab    = (float2*)(ws + 104857600);    // 2048x64 float2 = 1MB
  // attn partials reuse dead regions: Po in xb (512 x 32KB = 16.8MB), stats in wqkvT
  ushort_t* Po     = (ushort_t*)(ws + 0);
  float*    Pstat  = (float*)(ws + 17825792);      // 512 x 256 f32 = 512KB

  convert_f32_bf16<<<8192, 256, 0, stream>>>(x, xb, 2097152);
  transpose_to_bf16<<<dim3(64, 64), dim3(32, 8), 0, stream>>>(wq, wqkvT, 2048, 2048);
  transpose_to_bf16<<<dim3(32, 64), dim3(32, 8), 0, stream>>>(wkv, wkvT, 2048, 1024);
  transpose_to_bf16<<<dim3(64, 64), dim3(32, 8), 0, stream>>>(wproj, wprojT, 2048, 2048);
  rope_tab_k<<<512, 256, 0, stream>>>(omega, tab);

  // merged QKV projection: [4096,2048] @ [3072,2048]^T -> [4096,3072]
  gemm_bt<<<dim3(24, 32), 256, 0, stream>>>(xb, wqkvT, QKVraw, 4096, 3072, 2048);

  rope_q_k<<<16384, 256, 0, stream>>>(QKVraw, tab, Qb);
  rope_k_k<<<4096, 256, 0, stream>>>(QKVraw, tab, Kb);
  v_frag_k<<<1024, 256, 0, stream>>>(QKVraw, Vf);

  attn_k<<<dim3(24, 16, 2), 256, 0, stream>>>(Qb, Kb, Vf, Yb, Po, Pstat);
  merge_k<<<256, 256, 0, stream>>>(Po, Pstat, Yb);

  gemm_bt<<<dim3(16, 32), 256, 0, stream>>>(Yb, wprojT, out, 4096, 2048, 2048);
}

// Round 11
// 223.112 us; speedup vs baseline: 1.0829x; 1.0829x over previous
//
#include <hip/hip_runtime.h>
#include <hip/hip_bf16.h>

#define B_ 2
#define T_ 2048
#define C_ 2048
#define H_ 16
#define KH_ 4
#define D_ 128

typedef unsigned short ushort_t;
typedef __attribute__((ext_vector_type(8))) short short8;
typedef __attribute__((ext_vector_type(4))) float f32x4;

#define RSQRT_D 0.08838834764831845f
#define L2E 1.4426950408889634f
// Q pre-scale: 1/sqrt(D) * log2(e)  ->  QK^T lands in log2 units, softmax is pure exp2
#define QSCALE (0.08838834764831845f * 1.4426950408889634f)

__device__ __forceinline__ ushort_t f2b(float f) {
  union { float f; unsigned u; } v; v.f = f;
  unsigned r = v.u + 0x7fffu + ((v.u >> 16) & 1u);
  return (ushort_t)(r >> 16);
}
__device__ __forceinline__ float b2f(ushort_t u) {
  union { unsigned u; float f; } v; v.u = ((unsigned)u) << 16;
  return v.f;
}

__device__ __forceinline__ f32x4 mfma16(short8 a, short8 b, f32x4 c) {
  return __builtin_amdgcn_mfma_f32_16x16x32_bf16(a, b, c, 0, 0, 0);
}

__device__ __forceinline__ void async16(const void* g, void* l) {
  __builtin_amdgcn_global_load_lds(
      (const __attribute__((address_space(1))) void*)g,
      (__attribute__((address_space(3))) void*)l, 16, 0, 0);
}

// packed f32x2 -> bf16x2 (RTNE); dst.lo = bf16(lo), dst.hi = bf16(hi)
__device__ __forceinline__ unsigned cvtpk(float lo, float hi) {
  unsigned r;
  asm volatile("v_cvt_pk_bf16_f32 %0, %1, %2" : "=v"(r) : "v"(lo), "v"(hi));
  return r;
}

// ---------------- small prep kernels ----------------

__global__ void convert_f32_bf16(const float* __restrict__ in, ushort_t* __restrict__ out, int n4) {
  int i = blockIdx.x * blockDim.x + threadIdx.x;
  if (i >= n4) return;
  float4 v = ((const float4*)in)[i];
  ushort4 o;
  o.x = f2b(v.x); o.y = f2b(v.y); o.z = f2b(v.z); o.w = f2b(v.w);
  ((ushort4*)out)[i] = o;
}

// out[c][r] = bf16(in[r][c]);  in: R x C f32, out: C x R bf16
__global__ void transpose_to_bf16(const float* __restrict__ in, ushort_t* __restrict__ out, int R, int C) {
  __shared__ float tile[32][33];
  int c0 = blockIdx.x * 32, r0 = blockIdx.y * 32;
  int tx = threadIdx.x, ty = threadIdx.y;
#pragma unroll
  for (int i = 0; i < 4; i++) {
    int r = ty + i * 8;
    tile[r][tx] = in[(size_t)(r0 + r) * C + c0 + tx];
  }
  __syncthreads();
#pragma unroll
  for (int i = 0; i < 4; i++) {
    int r = ty + i * 8;
    out[(size_t)(c0 + r) * R + r0 + tx] = f2b(tile[tx][r]);
  }
}

// cos/sin table: tab[t*64+d] = (cos(t*omega[d]), sin(t*omega[d]))
__global__ void rope_tab_k(const float* __restrict__ omega, float2* __restrict__ tab) {
  int idx = blockIdx.x * blockDim.x + threadIdx.x;  // 2048*64
  int d = idx & 63;
  int t = idx >> 6;
  float ang = (float)t * omega[d];
  tab[idx] = make_float2(cosf(ang), sinf(ang));
}

// QKVraw [b*T+t][3072]: cols 0..2047 = q -> rope (pre-scaled by QSCALE) -> Qb [(b*16+h)*T + t][d]
__global__ void rope_q_k(const ushort_t* __restrict__ QKVraw, const float2* __restrict__ tab,
                         ushort_t* __restrict__ Qb) {
  int idx = blockIdx.x * blockDim.x + threadIdx.x;  // B*T*H*64 = 4194304
  int d = idx & 63;
  int h = (idx >> 6) & 15;
  int t = (idx >> 10) & 2047;
  int b = idx >> 21;
  size_t in_off = (size_t)(b * 2048 + t) * 3072 + h * 128 + d;
  float x1 = b2f(QKVraw[in_off]);
  float x2 = b2f(QKVraw[in_off + 64]);
  float2 cs = tab[t * 64 + d];
  size_t out_off = ((size_t)(b * 16 + h) * 2048 + t) * 128 + d;
  Qb[out_off] = f2b((x1 * cs.x - x2 * cs.y) * QSCALE);
  Qb[out_off + 64] = f2b((x1 * cs.y + x2 * cs.x) * QSCALE);
}

// QKVraw cols 2048..2559 = k -> rope -> Kb [(b*4+kh)*T + t][d]
__global__ void rope_k_k(const ushort_t* __restrict__ QKVraw, const float2* __restrict__ tab,
                         ushort_t* __restrict__ Kb) {
  int idx = blockIdx.x * blockDim.x + threadIdx.x;  // B*T*KH*64 = 1048576
  int d = idx & 63;
  int kh = (idx >> 6) & 3;
  int t = (idx >> 8) & 2047;
  int b = idx >> 19;
  size_t in_off = (size_t)(b * 2048 + t) * 3072 + 2048 + kh * 128 + d;
  float x1 = b2f(QKVraw[in_off]);
  float x2 = b2f(QKVraw[in_off + 64]);
  float2 cs = tab[t * 64 + d];
  size_t out_off = ((size_t)(b * 4 + kh) * 2048 + t) * 128 + d;
  Kb[out_off] = f2b(x1 * cs.x - x2 * cs.y);
  Kb[out_off + 64] = f2b(x1 * cs.y + x2 * cs.x);
}

// V fragment pre-pack: Vf short8 index = (((z*32+tile)*2+hv)*8+n)*64 + lane
// element j = V[b][t = tile*64 + kl][kh][d = n*16 + (lane&15)]
// kl = (hv*2 + ((j>>1)>>1))*16 + (lane>>4)*4 + 2*((j>>1)&1) + (j&1)
__global__ void v_frag_k(const ushort_t* __restrict__ QKVraw, ushort_t* __restrict__ Vf) {
  int idx = blockIdx.x * blockDim.x + threadIdx.x;  // 262144 short8 units
  int lane = idx & 63;
  int n = (idx >> 6) & 7;
  int hv = (idx >> 9) & 1;
  int tile = (idx >> 10) & 31;
  int z = idx >> 15;  // b*4+kh
  int b = z >> 2, kh = z & 3;
  int lr = lane & 15, lc = lane >> 4;
  int d = n * 16 + lr;
  union { ushort_t u[8]; short8 v; } out;
#pragma unroll
  for (int j = 0; j < 8; j++) {
    int tw = j >> 1, par = j & 1;
    int kl = (hv * 2 + (tw >> 1)) * 16 + lc * 4 + 2 * (tw & 1) + par;
    int t = tile * 64 + kl;
    out.u[j] = QKVraw[(size_t)(b * 2048 + t) * 3072 + 2560 + kh * 128 + d];
  }
  *(short8*)(Vf + (size_t)idx * 8) = out.v;
}

__device__ __forceinline__ void store_out(float* C, size_t idx, float v) { C[idx] = v; }
__device__ __forceinline__ void store_out(ushort_t* C, size_t idx, float v) { C[idx] = f2b(v); }

// ---------------- GEMM 128x128 (proj): 2-phase dbuf, counted vmcnt ----------------

template <typename OUT_T>
__global__ __launch_bounds__(256) void gemm_bt(const ushort_t* __restrict__ A,
                                               const ushort_t* __restrict__ Bt,
                                               OUT_T* __restrict__ C,
                                               int M, int N, int K) {
  __shared__ __attribute__((aligned(16))) ushort_t As[2][128 * 32];
  __shared__ __attribute__((aligned(16))) ushort_t Bs[2][128 * 32];
  const int tid = threadIdx.x;
  const int lane = tid & 63;
  const int w = tid >> 6;
  const int bm = blockIdx.y, bn = blockIdx.x;
  const int lr = lane & 15, lc = lane >> 4;
  const int wr = (w >> 1) * 64, wc = (w & 1) * 64;
  const ushort_t* Ab = A + (size_t)bm * 128 * K;
  const ushort_t* Bb = Bt + (size_t)bn * 128 * K;
  const int srow = tid >> 2;
  const int scol = (tid & 3) * 8;
  f32x4 acc[4][4];
#pragma unroll
  for (int i = 0; i < 4; i++)
#pragma unroll
    for (int j = 0; j < 4; j++) acc[i][j] = (f32x4)(0.0f);

  async16(Ab + (size_t)srow * K + scol, &As[0][0] + srow * 32 + scol);
  async16(Ab + (size_t)(srow + 64) * K + scol, &As[0][0] + (srow + 64) * 32 + scol);
  async16(Bb + (size_t)srow * K + scol, &Bs[0][0] + srow * 32 + scol);
  async16(Bb + (size_t)(srow + 64) * K + scol, &Bs[0][0] + (srow + 64) * 32 + scol);

  const int nt = K >> 5;
#pragma unroll 2
  for (int t = 0; t < nt - 1; t++) {
    const int cur = t & 1;
    {
      const int k1 = (t + 1) << 5;
      ushort_t* Ad = &As[cur ^ 1][0];
      ushort_t* Bd = &Bs[cur ^ 1][0];
      async16(Ab + (size_t)srow * K + k1 + scol, Ad + srow * 32 + scol);
      async16(Ab + (size_t)(srow + 64) * K + k1 + scol, Ad + (srow + 64) * 32 + scol);
      async16(Bb + (size_t)srow * K + k1 + scol, Bd + srow * 32 + scol);
      async16(Bb + (size_t)(srow + 64) * K + k1 + scol, Bd + (srow + 64) * 32 + scol);
    }
    asm volatile("s_waitcnt vmcnt(4)" ::: "memory");
    __builtin_amdgcn_s_barrier();
    __builtin_amdgcn_sched_barrier(0);
    const ushort_t* Al = &As[cur][0];
    const ushort_t* Bl = &Bs[cur][0];
    short8 af[4], bf[4];
#pragma unroll
    for (int mi = 0; mi < 4; mi++)
      af[mi] = *(const short8*)(Al + (wr + mi * 16 + lr) * 32 + lc * 8);
#pragma unroll
    for (int ni = 0; ni < 4; ni++)
      bf[ni] = *(const short8*)(Bl + (wc + ni * 16 + lr) * 32 + lc * 8);
#pragma unroll
    for (int mi = 0; mi < 4; mi++)
#pragma unroll
      for (int ni = 0; ni < 4; ni++)
        acc[mi][ni] = mfma16(af[mi], bf[ni], acc[mi][ni]);
    asm volatile("" ::: "memory");
    __builtin_amdgcn_s_barrier();
    asm volatile("" ::: "memory");
  }
  {
    const int cur = (nt - 1) & 1;
    asm volatile("s_waitcnt vmcnt(0)" ::: "memory");
    __builtin_amdgcn_s_barrier();
    __builtin_amdgcn_sched_barrier(0);
    const ushort_t* Al = &As[cur][0];
    const ushort_t* Bl = &Bs[cur][0];
    short8 af[4], bf[4];
#pragma unroll
    for (int mi = 0; mi < 4; mi++)
      af[mi] = *(const short8*)(Al + (wr + mi * 16 + lr) * 32 + lc * 8);
#pragma unroll
    for (int ni = 0; ni < 4; ni++)
      bf[ni] = *(const short8*)(Bl + (wc + ni * 16 + lr) * 32 + lc * 8);
#pragma unroll
    for (int mi = 0; mi < 4; mi++)
#pragma unroll
      for (int ni = 0; ni < 4; ni++)
        acc[mi][ni] = mfma16(af[mi], bf[ni], acc[mi][ni]);
  }
#pragma unroll
  for (int mi = 0; mi < 4; mi++) {
#pragma unroll
    for (int ni = 0; ni < 4; ni++) {
      int row = bm * 128 + wr + mi * 16 + lc * 4;
      int col = bn * 128 + wc + ni * 16 + lr;
#pragma unroll
      for (int r = 0; r < 4; r++)
        store_out(C, (size_t)(row + r) * N + col, acc[mi][ni][r]);
    }
  }
}

// ---------------- GEMM 256x256 8-phase (QKV): counted vmcnt(6), XOR-swizzled LDS ----
// BM=BN=256, BK=64 split into k0/k1 half-tiles of [256][32] bf16 (16KB each).
// 512 thr = 8 waves (2M x 4N); per-wave C = 128x64 (acc[8][4]). LDS 128KB dbuf.
// Phases per K-tile: (mq0,k0)(mq1,k0)(mq0,k1)(mq1,k1); reads 8/4/8/4 ds_read_b128,
// 16 MFMA each. Stage stream: tile t's P0..P3 stage tile t+1's [A_k0,B_k0,A_k1,B_k1];
// vmcnt(6) = 3 half-tiles in flight at P0/P2 (needed halves always >=3 phases old;
// verified for prologue, steady state, and tail; vmcnt(0) only at final P2).
// Swizzle: 16B-chunk = lc ^ ((row>>1)&3) -> rows 0..7 hit 8 distinct slots (2-way
// free); global source pre-swizzled with the same involution (both-sides rule).
template <typename OUT_T>
__global__ __launch_bounds__(512, 1) void gemm256(const ushort_t* __restrict__ A,
                                                  const ushort_t* __restrict__ Bt,
                                                  OUT_T* __restrict__ C,
                                                  int M, int N, int K) {
  __shared__ __attribute__((aligned(16))) ushort_t As[2][2][8192];
  __shared__ __attribute__((aligned(16))) ushort_t Bs[2][2][8192];
  const int tid = threadIdx.x;
  const int lane = tid & 63;
  const int w = tid >> 6;          // 0..7
  const int lr = lane & 15, lc = lane >> 4;
  const int wm = w >> 2, wn = w & 3;
  const int bm = blockIdx.y, bn = blockIdx.x;
  const ushort_t* Ab = A + (size_t)bm * 256 * K;
  const ushort_t* Bb = Bt + (size_t)bn * 256 * K;
  // staging: thread covers 16B units L0 = tid, L1 = 512 + tid of a 1024-unit half
  const int sr0 = tid >> 2, sc0 = tid & 3;
  const int sr1 = 128 + (tid >> 2), sc1 = tid & 3;

  f32x4 acc[8][4];
#pragma unroll
  for (int i = 0; i < 8; i++)
#pragma unroll
    for (int j = 0; j < 4; j++) acc[i][j] = (f32x4)(0.0f);

  auto STAGE = [&](int kt, int hid) {
    const int buf = kt & 1;
    const int kk = hid >> 1;
    const ushort_t* gb = (hid & 1) ? Bb : Ab;
    ushort_t* db = (hid & 1) ? &Bs[buf][kk][0] : &As[buf][kk][0];
    const int kbase = kt * 64 + kk * 32;
    {
      const int lch = sc0 ^ ((sr0 >> 1) & 3);
      async16(gb + (size_t)sr0 * K + kbase + lch * 8, db + (sr0 * 4 + sc0) * 8);
    }
    {
      const int lch = sc1 ^ ((sr1 >> 1) & 3);
      async16(gb + (size_t)sr1 * K + kbase + lch * 8, db + (sr1 * 4 + sc1) * 8);
    }
  };

  const int nt = K >> 6;
  // prologue: tile 0's four halves
  STAGE(0, 0); STAGE(0, 1); STAGE(0, 2); STAGE(0, 3);

#pragma unroll 1
  for (int t = 0; t < nt; ++t) {
    const int buf = t & 1;
    const ushort_t* Ak0 = &As[buf][0][0];
    const ushort_t* Ak1 = &As[buf][1][0];
    const ushort_t* Bk0 = &Bs[buf][0][0];
    const ushort_t* Bk1 = &Bs[buf][1][0];
    short8 af[4], bf[4];

    // ---- P0: stage t+1.A_k0; vmcnt(6); barrier; read B_k0 + A[mq0,k0]; MFMA mq0
    if (t + 1 < nt) STAGE(t + 1, 0);
    asm volatile("s_waitcnt vmcnt(6)" ::: "memory");
    __builtin_amdgcn_s_barrier();
    __builtin_amdgcn_sched_barrier(0);
#pragma unroll
    for (int nf = 0; nf < 4; nf++) {
      const int row = wn * 64 + nf * 16 + lr;
      bf[nf] = *(const short8*)(Bk0 + row * 32 + ((lc ^ ((row >> 1) & 3)) * 8));
    }
#pragma unroll
    for (int mf = 0; mf < 4; mf++) {
      const int row = wm * 128 + mf * 16 + lr;
      af[mf] = *(const short8*)(Ak0 + row * 32 + ((lc ^ ((row >> 1) & 3)) * 8));
    }
    __builtin_amdgcn_s_setprio(1);
#pragma unroll
    for (int mf = 0; mf < 4; mf++)
#pragma unroll
      for (int nf = 0; nf < 4; nf++)
        acc[mf][nf] = mfma16(af[mf], bf[nf], acc[mf][nf]);
    __builtin_amdgcn_s_setprio(0);

    // ---- P1: stage t+1.B_k0; barrier; read A[mq1,k0]; MFMA mq1 (bf reused)
    if (t + 1 < nt) STAGE(t + 1, 1);
    asm volatile("" ::: "memory");
    __builtin_amdgcn_s_barrier();
    __builtin_amdgcn_sched_barrier(0);
#pragma unroll
    for (int mf = 0; mf < 4; mf++) {
      const int row = wm * 128 + 64 + mf * 16 + lr;
      af[mf] = *(const short8*)(Ak0 + row * 32 + ((lc ^ ((row >> 1) & 3)) * 8));
    }
    __builtin_amdgcn_s_setprio(1);
#pragma unroll
    for (int mf = 0; mf < 4; mf++)
#pragma unroll
      for (int nf = 0; nf < 4; nf++)
        acc[4 + mf][nf] = mfma16(af[mf], bf[nf], acc[4 + mf][nf]);
    __builtin_amdgcn_s_setprio(0);

    // ---- P2: stage t+1.A_k1; vmcnt(6|0); barrier; read B_k1 + A[mq0,k1]; MFMA mq0
    if (t + 1 < nt) STAGE(t + 1, 2);
    if (t == nt - 1) {
      asm volatile("s_waitcnt vmcnt(0)" ::: "memory");
    } else {
      asm volatile("s_waitcnt vmcnt(6)" ::: "memory");
    }
    __builtin_amdgcn_s_barrier();
    __builtin_amdgcn_sched_barrier(0);
#pragma unroll
    for (int nf = 0; nf < 4; nf++) {
      const int row = wn * 64 + nf * 16 + lr;
      bf[nf] = *(const short8*)(Bk1 + row * 32 + ((lc ^ ((row >> 1) & 3)) * 8));
    }
#pragma unroll
    for (int mf = 0; mf < 4; mf++) {
      const int row = wm * 128 + mf * 16 + lr;
      af[mf] = *(const short8*)(Ak1 + row * 32 + ((lc ^ ((row >> 1) & 3)) * 8));
    }
    __builtin_amdgcn_s_setprio(1);
#pragma unroll
    for (int mf = 0; mf < 4; mf++)
#pragma unroll
      for (int nf = 0; nf < 4; nf++)
        acc[mf][nf] = mfma16(af[mf], bf[nf], acc[mf][nf]);
    __builtin_amdgcn_s_setprio(0);

    // ---- P3: stage t+1.B_k1; barrier; read A[mq1,k1]; MFMA mq1
    if (t + 1 < nt) STAGE(t + 1, 3);
    asm volatile("" ::: "memory");
    __builtin_amdgcn_s_barrier();
    __builtin_amdgcn_sched_barrier(0);
#pragma unroll
    for (int mf = 0; mf < 4; mf++) {
      const int row = wm * 128 + 64 + mf * 16 + lr;
      af[mf] = *(const short8*)(Ak1 + row * 32 + ((lc ^ ((row >> 1) & 3)) * 8));
    }
    __builtin_amdgcn_s_setprio(1);
#pragma unroll
    for (int mf = 0; mf < 4; mf++)
#pragma unroll
      for (int nf = 0; nf < 4; nf++)
        acc[4 + mf][nf] = mfma16(af[mf], bf[nf], acc[4 + mf][nf]);
    __builtin_amdgcn_s_setprio(0);
  }

#pragma unroll
  for (int mfp = 0; mfp < 8; mfp++) {
#pragma unroll
    for (int nf = 0; nf < 4; nf++) {
      const int row = bm * 256 + wm * 128 + mfp * 16 + lc * 4;
      const int col = bn * 256 + wn * 64 + nf * 16 + lr;
#pragma unroll
      for (int r = 0; r < 4; r++)
        store_out(C, (size_t)(row + r) * N + col, acc[mfp][nf][r]);
    }
  }
}

// ---------------- flash attention (causal GQA) — R9 config (best: 76us) ----------------
__global__ __launch_bounds__(256, 2) void attn_k(const ushort_t* __restrict__ Qb,
                                                 const ushort_t* __restrict__ Kb,
                                                 const ushort_t* __restrict__ Vf,
                                                 ushort_t* __restrict__ Yb) {
  __shared__ __attribute__((aligned(16))) ushort_t Ks[2][64 * 128];  // 32 KB
  const int tid = threadIdx.x;
  const int lane = tid & 63;
  const int w = tid >> 6;
  const int lr = lane & 15, lc = lane >> 4;
  const int gy = blockIdx.y;
  const int h = gy;
  const int b = blockIdx.z;
  const int kh = h >> 2;
  const int qc = b ? (15 - ((blockIdx.x + gy) & 15)) : ((blockIdx.x + gy) & 15);
  const int q0w = qc * 128 + w * 32;

  const ushort_t* Qp = Qb + (size_t)(b * 16 + h) * T_ * D_;
  const ushort_t* Kp = Kb + (size_t)(b * 4 + kh) * T_ * D_;
  const ushort_t* Vfb = Vf + (size_t)(b * 4 + kh) * 262144;

  const int st_row = tid >> 4;
  const int st_slot = tid & 15;

  short8 qf[2][4];
#pragma unroll
  for (int f = 0; f < 2; f++)
#pragma unroll
    for (int c = 0; c < 4; c++)
      qf[f][c] = *(const short8*)(Qp + (size_t)(q0w + f * 16 + lr) * D_ + c * 32 + lc * 8);

  f32x4 o[2][8];
#pragma unroll
  for (int f = 0; f < 2; f++)
#pragma unroll
    for (int n = 0; n < 8; n++) o[f][n] = (f32x4)(0.0f);
  float m[2] = {-1e30f, -1e30f}, l[2] = {0.0f, 0.0f};

  const int nt = 2 * qc + 2;

#pragma unroll
  for (int i = 0; i < 4; i++) {
    int row = i * 16 + st_row;
    async16(Kp + (size_t)row * D_ + (((st_slot - row) & 15) * 8),
            &Ks[0][0] + row * 128 + st_slot * 8);
  }

#pragma unroll 1
  for (int ti = 0; ti < nt; ti++) {
    __syncthreads();
    const int kv0 = ti * 64;
    if (ti + 1 < nt) {
      const ushort_t* Kn = Kp + (size_t)(kv0 + 64) * D_;
      ushort_t* dst = &Ks[(ti + 1) & 1][0];
#pragma unroll
      for (int i = 0; i < 4; i++) {
        int row = i * 16 + st_row;
        async16(Kn + (size_t)row * D_ + (((st_slot - row) & 15) * 8),
                dst + row * 128 + st_slot * 8);
      }
    }
    if (kv0 > q0w + 31) continue;
    const ushort_t* Kl = &Ks[ti & 1][0];
    const ushort_t* Vt0 = Vfb + (size_t)(ti * 2) * 4096;
    short8 vr0[8];
#pragma unroll
    for (int n = 0; n < 8; n++)
      vr0[n] = *(const short8*)(Vt0 + n * 512 + lane * 8);
    f32x4 s[2][4];
#pragma unroll
    for (int f = 0; f < 2; f++)
#pragma unroll
      for (int kj = 0; kj < 4; kj++) s[f][kj] = (f32x4)(0.0f);
    __builtin_amdgcn_s_setprio(1);
#pragma unroll
    for (int c = 0; c < 4; c++) {
      short8 kf[4];
#pragma unroll
      for (int kj = 0; kj < 4; kj++)
        kf[kj] = *(const short8*)(Kl + (kj * 16 + lr) * 128 + (((c * 4 + lc + lr) & 15) * 8));
#pragma unroll
      for (int f = 0; f < 2; f++)
#pragma unroll
        for (int kj = 0; kj < 4; kj++)
          s[f][kj] = mfma16(kf[kj], qf[f][c], s[f][kj]);
    }
    __builtin_amdgcn_s_setprio(0);
    const ushort_t* Vt1 = Vfb + (size_t)(ti * 2 + 1) * 4096;
    short8 vr1[8];
#pragma unroll
    for (int n = 0; n < 8; n++)
      vr1[n] = *(const short8*)(Vt1 + n * 512 + lane * 8);
    const bool maskt = (kv0 + 63 > q0w);
    union { unsigned u[4]; short8 v; } pa0[2], pa1[2];
#pragma unroll
    for (int f = 0; f < 2; f++) {
      const int q = q0w + f * 16 + lr;
      float pv[16];
      float mx = -1e30f;
      if (maskt) {
#pragma unroll
        for (int kj = 0; kj < 4; kj++)
#pragma unroll
          for (int r = 0; r < 4; r++) {
            float a = s[f][kj][r];
            if (kv0 + kj * 16 + lc * 4 + r > q) a = -1e30f;
            pv[kj * 4 + r] = a;
            mx = fmaxf(mx, a);
          }
      } else {
#pragma unroll
        for (int kj = 0; kj < 4; kj++)
#pragma unroll
          for (int r = 0; r < 4; r++) {
            float a = s[f][kj][r];
            pv[kj * 4 + r] = a;
            mx = fmaxf(mx, a);
          }
      }
      mx = fmaxf(mx, __shfl_xor(mx, 16));
      mx = fmaxf(mx, __shfl_xor(mx, 32));
      const bool need = __any(mx > m[f] + 8.0f);
      const float mn = need ? fmaxf(m[f], mx) : m[f];
      float rs = 0.0f;
#pragma unroll
      for (int i = 0; i < 16; i++) {
        pv[i] = exp2f(pv[i] - mn);
        rs += pv[i];
      }
      rs += __shfl_xor(rs, 16);
      rs += __shfl_xor(rs, 32);
#pragma unroll
      for (int kj = 0; kj < 2; kj++) {
        pa0[f].u[kj * 2] = cvtpk(pv[kj * 4], pv[kj * 4 + 1]);
        pa0[f].u[kj * 2 + 1] = cvtpk(pv[kj * 4 + 2], pv[kj * 4 + 3]);
        pa1[f].u[kj * 2] = cvtpk(pv[8 + kj * 4], pv[8 + kj * 4 + 1]);
        pa1[f].u[kj * 2 + 1] = cvtpk(pv[8 + kj * 4 + 2], pv[8 + kj * 4 + 3]);
      }
      if (need) {
        float al = exp2f(m[f] - mn);
        m[f] = mn;
        l[f] = l[f] * al + rs;
        float alT[4];
#pragma unroll
        for (int r = 0; r < 4; r++)
          alT[r] = __shfl(al, (lane & 48) | (lc * 4 + r));
#pragma unroll
        for (int n = 0; n < 8; n++)
#pragma unroll
          for (int r = 0; r < 4; r++) o[f][n][r] *= alT[r];
      } else {
        l[f] += rs;
      }
    }
    __builtin_amdgcn_s_setprio(1);
#pragma unroll
    for (int n = 0; n < 8; n++) {
      o[0][n] = mfma16(pa0[0].v, vr0[n], o[0][n]);
      o[1][n] = mfma16(pa0[1].v, vr0[n], o[1][n]);
    }
#pragma unroll
    for (int n = 0; n < 8; n++) {
      o[0][n] = mfma16(pa1[0].v, vr1[n], o[0][n]);
      o[1][n] = mfma16(pa1[1].v, vr1[n], o[1][n]);
    }
    __builtin_amdgcn_s_setprio(0);
  }
#pragma unroll
  for (int f = 0; f < 2; f++) {
    float inv = 1.0f / l[f];
    float invT[4];
#pragma unroll
    for (int r = 0; r < 4; r++)
      invT[r] = __shfl(inv, (lane & 48) | (lc * 4 + r));
#pragma unroll
    for (int n = 0; n < 8; n++)
#pragma unroll
      for (int r = 0; r < 4; r++) {
        int qo = q0w + f * 16 + lc * 4 + r;
        int d = n * 16 + lr;
        Yb[(size_t)(b * T_ + qo) * 2048 + h * 128 + d] = f2b(o[f][n][r] * invT[r]);
      }
  }
}

// ---------------- launch ----------------

extern "C" void kernel_launch(void* const* d_in, const int* in_sizes, int n_in,
                              void* d_out, int out_size, void* d_ws, size_t ws_size,
                              hipStream_t stream) {
  (void)in_sizes; (void)n_in; (void)out_size; (void)ws_size;
  const float* x = (const float*)d_in[0];
  const float* wq = (const float*)d_in[1];
  const float* wkv = (const float*)d_in[2];
  const float* wproj = (const float*)d_in[3];
  const float* omega = (const float*)d_in[4];
  float* out = (float*)d_out;
  char* ws = (char*)d_ws;

  ushort_t* xb     = (ushort_t*)(ws + 0);          // 4096x2048 bf16 = 16.8MB
  ushort_t* wqkvT  = (ushort_t*)(ws + 16777216);   // [3072][2048] bf16 (wqT then wkvT)
  ushort_t* wkvT   = (ushort_t*)(ws + 25165824);   // tail of wqkvT
  ushort_t* wprojT = (ushort_t*)(ws + 29360128);   // 2048x2048 bf16
  ushort_t* QKVraw = (ushort_t*)(ws + 37748736);   // 4096x3072 bf16 = 25.2MB
  ushort_t* Qb     = (ushort_t*)(ws + 62914560);   // [b][h][t][d] bf16
  ushort_t* Kb     = (ushort_t*)(ws + 79691776);   // [b][kh][t][d] bf16
  ushort_t* Vf     = (ushort_t*)(ws + 83886080);   // V fragment-packed, 4MB
  ushort_t* Yb     = (ushort_t*)(ws + 88080384);   // 4096x2048 bf16
  float2*   tab    = (float2*)(ws + 104857600);    // 2048x64 float2 = 1MB

  convert_f32_bf16<<<8192, 256, 0, stream>>>(x, xb, 2097152);
  transpose_to_bf16<<<dim3(64, 64), dim3(32, 8), 0, stream>>>(wq, wqkvT, 2048, 2048);
  transpose_to_bf16<<<dim3(32, 64), dim3(32, 8), 0, stream>>>(wkv, wkvT, 2048, 1024);
  transpose_to_bf16<<<dim3(64, 64), dim3(32, 8), 0, stream>>>(wproj, wprojT, 2048, 2048);
  rope_tab_k<<<512, 256, 0, stream>>>(omega, tab);

  // merged QKV projection via 256^2 8-phase: [4096,2048] @ [3072,2048]^T -> [4096,3072]
  gemm256<<<dim3(12, 16), 512, 0, stream>>>(xb, wqkvT, QKVraw, 4096, 3072, 2048);

  rope_q_k<<<16384, 256, 0, stream>>>(QKVraw, tab, Qb);
  rope_k_k<<<4096, 256, 0, stream>>>(QKVraw, tab, Kb);
  v_frag_k<<<1024, 256, 0, stream>>>(QKVraw, Vf);

  attn_k<<<dim3(16, 16, 2), 256, 0, stream>>>(Qb, Kb, Vf, Yb);

  gemm_bt<<<dim3(16, 32), 256, 0, stream>>>(Yb, wprojT, out, 4096, 2048, 2048);
}

// Round 12
// 221.266 us; speedup vs baseline: 1.0920x; 1.0083x over previous
//
#include <hip/hip_runtime.h>
#include <hip/hip_bf16.h>

#define B_ 2
#define T_ 2048
#define C_ 2048
#define H_ 16
#define KH_ 4
#define D_ 128

typedef unsigned short ushort_t;
typedef __attribute__((ext_vector_type(8))) short short8;
typedef __attribute__((ext_vector_type(4))) float f32x4;

#define RSQRT_D 0.08838834764831845f
#define L2E 1.4426950408889634f
// Q pre-scale: 1/sqrt(D) * log2(e)  ->  QK^T lands in log2 units, softmax is pure exp2
#define QSCALE (0.08838834764831845f * 1.4426950408889634f)

__device__ __forceinline__ ushort_t f2b(float f) {
  union { float f; unsigned u; } v; v.f = f;
  unsigned r = v.u + 0x7fffu + ((v.u >> 16) & 1u);
  return (ushort_t)(r >> 16);
}
__device__ __forceinline__ float b2f(ushort_t u) {
  union { unsigned u; float f; } v; v.u = ((unsigned)u) << 16;
  return v.f;
}

__device__ __forceinline__ f32x4 mfma16(short8 a, short8 b, f32x4 c) {
  return __builtin_amdgcn_mfma_f32_16x16x32_bf16(a, b, c, 0, 0, 0);
}

__device__ __forceinline__ void async16(const void* g, void* l) {
  __builtin_amdgcn_global_load_lds(
      (const __attribute__((address_space(1))) void*)g,
      (__attribute__((address_space(3))) void*)l, 16, 0, 0);
}

// packed f32x2 -> bf16x2 (RTNE); dst.lo = bf16(lo), dst.hi = bf16(hi)
__device__ __forceinline__ unsigned cvtpk(float lo, float hi) {
  unsigned r;
  asm volatile("v_cvt_pk_bf16_f32 %0, %1, %2" : "=v"(r) : "v"(lo), "v"(hi));
  return r;
}

// ---------------- small prep kernels ----------------

__global__ void convert_f32_bf16(const float* __restrict__ in, ushort_t* __restrict__ out, int n4) {
  int i = blockIdx.x * blockDim.x + threadIdx.x;
  if (i >= n4) return;
  float4 v = ((const float4*)in)[i];
  ushort4 o;
  o.x = f2b(v.x); o.y = f2b(v.y); o.z = f2b(v.z); o.w = f2b(v.w);
  ((ushort4*)out)[i] = o;
}

// out[c][r] = bf16(in[r][c]);  in: R x C f32, out: C x R bf16
__global__ void transpose_to_bf16(const float* __restrict__ in, ushort_t* __restrict__ out, int R, int C) {
  __shared__ float tile[32][33];
  int c0 = blockIdx.x * 32, r0 = blockIdx.y * 32;
  int tx = threadIdx.x, ty = threadIdx.y;
#pragma unroll
  for (int i = 0; i < 4; i++) {
    int r = ty + i * 8;
    tile[r][tx] = in[(size_t)(r0 + r) * C + c0 + tx];
  }
  __syncthreads();
#pragma unroll
  for (int i = 0; i < 4; i++) {
    int r = ty + i * 8;
    out[(size_t)(c0 + r) * R + r0 + tx] = f2b(tile[tx][r]);
  }
}

// cos/sin table: tab[t*64+d] = (cos(t*omega[d]), sin(t*omega[d]))
__global__ void rope_tab_k(const float* __restrict__ omega, float2* __restrict__ tab) {
  int idx = blockIdx.x * blockDim.x + threadIdx.x;  // 2048*64
  int d = idx & 63;
  int t = idx >> 6;
  float ang = (float)t * omega[d];
  tab[idx] = make_float2(cosf(ang), sinf(ang));
}

// QKVraw [b*T+t][3072]: cols 0..2047 = q -> rope (pre-scaled by QSCALE) -> Qb [(b*16+h)*T + t][d]
__global__ void rope_q_k(const ushort_t* __restrict__ QKVraw, const float2* __restrict__ tab,
                         ushort_t* __restrict__ Qb) {
  int idx = blockIdx.x * blockDim.x + threadIdx.x;  // B*T*H*64 = 4194304
  int d = idx & 63;
  int h = (idx >> 6) & 15;
  int t = (idx >> 10) & 2047;
  int b = idx >> 21;
  size_t in_off = (size_t)(b * 2048 + t) * 3072 + h * 128 + d;
  float x1 = b2f(QKVraw[in_off]);
  float x2 = b2f(QKVraw[in_off + 64]);
  float2 cs = tab[t * 64 + d];
  size_t out_off = ((size_t)(b * 16 + h) * 2048 + t) * 128 + d;
  Qb[out_off] = f2b((x1 * cs.x - x2 * cs.y) * QSCALE);
  Qb[out_off + 64] = f2b((x1 * cs.y + x2 * cs.x) * QSCALE);
}

// QKVraw cols 2048..2559 = k -> rope -> Kb [(b*4+kh)*T + t][d]
__global__ void rope_k_k(const ushort_t* __restrict__ QKVraw, const float2* __restrict__ tab,
                         ushort_t* __restrict__ Kb) {
  int idx = blockIdx.x * blockDim.x + threadIdx.x;  // B*T*KH*64 = 1048576
  int d = idx & 63;
  int kh = (idx >> 6) & 3;
  int t = (idx >> 8) & 2047;
  int b = idx >> 19;
  size_t in_off = (size_t)(b * 2048 + t) * 3072 + 2048 + kh * 128 + d;
  float x1 = b2f(QKVraw[in_off]);
  float x2 = b2f(QKVraw[in_off + 64]);
  float2 cs = tab[t * 64 + d];
  size_t out_off = ((size_t)(b * 4 + kh) * 2048 + t) * 128 + d;
  Kb[out_off] = f2b(x1 * cs.x - x2 * cs.y);
  Kb[out_off + 64] = f2b(x1 * cs.y + x2 * cs.x);
}

// V fragment pre-pack: Vf short8 index = (((z*32+tile)*2+hv)*8+n)*64 + lane
// element j = V[b][t = tile*64 + kl][kh][d = n*16 + (lane&15)]
// kl = (hv*2 + ((j>>1)>>1))*16 + (lane>>4)*4 + 2*((j>>1)&1) + (j&1)
__global__ void v_frag_k(const ushort_t* __restrict__ QKVraw, ushort_t* __restrict__ Vf) {
  int idx = blockIdx.x * blockDim.x + threadIdx.x;  // 262144 short8 units
  int lane = idx & 63;
  int n = (idx >> 6) & 7;
  int hv = (idx >> 9) & 1;
  int tile = (idx >> 10) & 31;
  int z = idx >> 15;  // b*4+kh
  int b = z >> 2, kh = z & 3;
  int lr = lane & 15, lc = lane >> 4;
  int d = n * 16 + lr;
  union { ushort_t u[8]; short8 v; } out;
#pragma unroll
  for (int j = 0; j < 8; j++) {
    int tw = j >> 1, par = j & 1;
    int kl = (hv * 2 + (tw >> 1)) * 16 + lc * 4 + 2 * (tw & 1) + par;
    int t = tile * 64 + kl;
    out.u[j] = QKVraw[(size_t)(b * 2048 + t) * 3072 + 2560 + kh * 128 + d];
  }
  *(short8*)(Vf + (size_t)idx * 8) = out.v;
}

__device__ __forceinline__ void store_out(float* C, size_t idx, float v) { C[idx] = v; }
__device__ __forceinline__ void store_out(ushort_t* C, size_t idx, float v) { C[idx] = f2b(v); }

// ---------------- GEMM 128x128 (proj): 2-phase dbuf, counted vmcnt ----------------

template <typename OUT_T>
__global__ __launch_bounds__(256) void gemm_bt(const ushort_t* __restrict__ A,
                                               const ushort_t* __restrict__ Bt,
                                               OUT_T* __restrict__ C,
                                               int M, int N, int K) {
  __shared__ __attribute__((aligned(16))) ushort_t As[2][128 * 32];
  __shared__ __attribute__((aligned(16))) ushort_t Bs[2][128 * 32];
  const int tid = threadIdx.x;
  const int lane = tid & 63;
  const int w = tid >> 6;
  const int bm = blockIdx.y, bn = blockIdx.x;
  const int lr = lane & 15, lc = lane >> 4;
  const int wr = (w >> 1) * 64, wc = (w & 1) * 64;
  const ushort_t* Ab = A + (size_t)bm * 128 * K;
  const ushort_t* Bb = Bt + (size_t)bn * 128 * K;
  const int srow = tid >> 2;
  const int scol = (tid & 3) * 8;
  f32x4 acc[4][4];
#pragma unroll
  for (int i = 0; i < 4; i++)
#pragma unroll
    for (int j = 0; j < 4; j++) acc[i][j] = (f32x4)(0.0f);

  async16(Ab + (size_t)srow * K + scol, &As[0][0] + srow * 32 + scol);
  async16(Ab + (size_t)(srow + 64) * K + scol, &As[0][0] + (srow + 64) * 32 + scol);
  async16(Bb + (size_t)srow * K + scol, &Bs[0][0] + srow * 32 + scol);
  async16(Bb + (size_t)(srow + 64) * K + scol, &Bs[0][0] + (srow + 64) * 32 + scol);

  const int nt = K >> 5;
#pragma unroll 2
  for (int t = 0; t < nt - 1; t++) {
    const int cur = t & 1;
    {
      const int k1 = (t + 1) << 5;
      ushort_t* Ad = &As[cur ^ 1][0];
      ushort_t* Bd = &Bs[cur ^ 1][0];
      async16(Ab + (size_t)srow * K + k1 + scol, Ad + srow * 32 + scol);
      async16(Ab + (size_t)(srow + 64) * K + k1 + scol, Ad + (srow + 64) * 32 + scol);
      async16(Bb + (size_t)srow * K + k1 + scol, Bd + srow * 32 + scol);
      async16(Bb + (size_t)(srow + 64) * K + k1 + scol, Bd + (srow + 64) * 32 + scol);
    }
    asm volatile("s_waitcnt vmcnt(4)" ::: "memory");
    __builtin_amdgcn_s_barrier();
    __builtin_amdgcn_sched_barrier(0);
    const ushort_t* Al = &As[cur][0];
    const ushort_t* Bl = &Bs[cur][0];
    short8 af[4], bf[4];
#pragma unroll
    for (int mi = 0; mi < 4; mi++)
      af[mi] = *(const short8*)(Al + (wr + mi * 16 + lr) * 32 + lc * 8);
#pragma unroll
    for (int ni = 0; ni < 4; ni++)
      bf[ni] = *(const short8*)(Bl + (wc + ni * 16 + lr) * 32 + lc * 8);
#pragma unroll
    for (int mi = 0; mi < 4; mi++)
#pragma unroll
      for (int ni = 0; ni < 4; ni++)
        acc[mi][ni] = mfma16(af[mi], bf[ni], acc[mi][ni]);
    asm volatile("" ::: "memory");
    __builtin_amdgcn_s_barrier();
    asm volatile("" ::: "memory");
  }
  {
    const int cur = (nt - 1) & 1;
    asm volatile("s_waitcnt vmcnt(0)" ::: "memory");
    __builtin_amdgcn_s_barrier();
    __builtin_amdgcn_sched_barrier(0);
    const ushort_t* Al = &As[cur][0];
    const ushort_t* Bl = &Bs[cur][0];
    short8 af[4], bf[4];
#pragma unroll
    for (int mi = 0; mi < 4; mi++)
      af[mi] = *(const short8*)(Al + (wr + mi * 16 + lr) * 32 + lc * 8);
#pragma unroll
    for (int ni = 0; ni < 4; ni++)
      bf[ni] = *(const short8*)(Bl + (wc + ni * 16 + lr) * 32 + lc * 8);
#pragma unroll
    for (int mi = 0; mi < 4; mi++)
#pragma unroll
      for (int ni = 0; ni < 4; ni++)
        acc[mi][ni] = mfma16(af[mi], bf[ni], acc[mi][ni]);
  }
#pragma unroll
  for (int mi = 0; mi < 4; mi++) {
#pragma unroll
    for (int ni = 0; ni < 4; ni++) {
      int row = bm * 128 + wr + mi * 16 + lc * 4;
      int col = bn * 128 + wc + ni * 16 + lr;
#pragma unroll
      for (int r = 0; r < 4; r++)
        store_out(C, (size_t)(row + r) * N + col, acc[mi][ni][r]);
    }
  }
}

// ---------------- GEMM 256x256 8-phase (QKV) — m201 phase order ----------------
// BM=BN=256, BK=64 as k0/k1 halves of [256][32] (16KB). 512 thr = 8 waves (2Mx4N).
// Phase = { ds_read subtile (reads data PUBLISHED by an earlier vmcnt+barrier) ;
//           STAGE one t+1 half ; barrier ; lgkmcnt(0)+sched_barrier ; setprio(1)
//           16 MFMA setprio(0) ; [vmcnt(4) at P1/P3 publishing the next reads] ;
//           barrier }.  Early ds_read overlaps other waves' MFMA drain (the m196
// interleave). vmcnt(4) keeps one half-tile pair in flight; publishing barrier
// follows every vmcnt so OTHER waves' staged rows are visible before any read.
// Prologue: 4 STAGEs, vmcnt(4), barrier. Tail: vmcnt(0) at P1, none at P3.
// Swizzle: chunk = lc ^ ((row>>1)&3), source pre-swizzled (both-sides).
// Grid: 1D 192 blocks, XCD-bijective swz (192%8==0): 24 consecutive per XCD.
template <typename OUT_T>
__global__ __launch_bounds__(512, 1) void gemm256(const ushort_t* __restrict__ A,
                                                  const ushort_t* __restrict__ Bt,
                                                  OUT_T* __restrict__ C,
                                                  int M, int N, int K) {
  __shared__ __attribute__((aligned(16))) ushort_t As[2][2][8192];
  __shared__ __attribute__((aligned(16))) ushort_t Bs[2][2][8192];
  const int tid = threadIdx.x;
  const int lane = tid & 63;
  const int w = tid >> 6;          // 0..7
  const int lr = lane & 15, lc = lane >> 4;
  const int wm = w >> 2, wn = w & 3;
  // XCD-aware bijective swizzle over 1D grid
  const int nwg = gridDim.x;
  const int cpx = nwg >> 3;        // requires nwg % 8 == 0
  const int swz = (blockIdx.x & 7) * cpx + (blockIdx.x >> 3);
  const int bnc = N >> 8;
  const int bm = swz / bnc, bn = swz % bnc;
  const ushort_t* Ab = A + (size_t)bm * 256 * K;
  const ushort_t* Bb = Bt + (size_t)bn * 256 * K;
  const int sr0 = tid >> 2, sc0 = tid & 3;
  const int sr1 = 128 + (tid >> 2), sc1 = tid & 3;

  f32x4 acc[8][4];
#pragma unroll
  for (int i = 0; i < 8; i++)
#pragma unroll
    for (int j = 0; j < 4; j++) acc[i][j] = (f32x4)(0.0f);

  auto STAGE = [&](int kt, int hid) {
    const int buf = kt & 1;
    const int kk = hid >> 1;
    const ushort_t* gb = (hid & 1) ? Bb : Ab;
    ushort_t* db = (hid & 1) ? &Bs[buf][kk][0] : &As[buf][kk][0];
    const int kbase = kt * 64 + kk * 32;
    {
      const int lch = sc0 ^ ((sr0 >> 1) & 3);
      async16(gb + (size_t)sr0 * K + kbase + lch * 8, db + (sr0 * 4 + sc0) * 8);
    }
    {
      const int lch = sc1 ^ ((sr1 >> 1) & 3);
      async16(gb + (size_t)sr1 * K + kbase + lch * 8, db + (sr1 * 4 + sc1) * 8);
    }
  };

  const int nt = K >> 6;
  // prologue: stage tile0 fully; publish A_k0/B_k0 (keep A_k1/B_k1 in flight)
  STAGE(0, 0); STAGE(0, 1); STAGE(0, 2); STAGE(0, 3);
  asm volatile("s_waitcnt vmcnt(4)" ::: "memory");
  __builtin_amdgcn_s_barrier();

#pragma unroll 1
  for (int t = 0; t < nt; ++t) {
    const int buf = t & 1;
    const ushort_t* Ak0 = &As[buf][0][0];
    const ushort_t* Ak1 = &As[buf][1][0];
    const ushort_t* Bk0 = &Bs[buf][0][0];
    const ushort_t* Bk1 = &Bs[buf][1][0];
    short8 af[4], bf[4];

    // ---- P0: ds B_k0 + A[mq0,k0] (published at t-1 P3); stage t+1.A_k0
#pragma unroll
    for (int nf = 0; nf < 4; nf++) {
      const int row = wn * 64 + nf * 16 + lr;
      bf[nf] = *(const short8*)(Bk0 + row * 32 + ((lc ^ ((row >> 1) & 3)) * 8));
    }
#pragma unroll
    for (int mf = 0; mf < 4; mf++) {
      const int row = wm * 128 + mf * 16 + lr;
      af[mf] = *(const short8*)(Ak0 + row * 32 + ((lc ^ ((row >> 1) & 3)) * 8));
    }
    if (t + 1 < nt) STAGE(t + 1, 0);
    __builtin_amdgcn_s_barrier();
    asm volatile("s_waitcnt lgkmcnt(0)" ::: "memory");
    __builtin_amdgcn_sched_barrier(0);
    __builtin_amdgcn_s_setprio(1);
#pragma unroll
    for (int mf = 0; mf < 4; mf++)
#pragma unroll
      for (int nf = 0; nf < 4; nf++)
        acc[mf][nf] = mfma16(af[mf], bf[nf], acc[mf][nf]);
    __builtin_amdgcn_s_setprio(0);
    __builtin_amdgcn_s_barrier();

    // ---- P1: ds A[mq1,k0]; stage t+1.B_k0; MFMA; vmcnt(4) publishes A_k1/B_k1
#pragma unroll
    for (int mf = 0; mf < 4; mf++) {
      const int row = wm * 128 + 64 + mf * 16 + lr;
      af[mf] = *(const short8*)(Ak0 + row * 32 + ((lc ^ ((row >> 1) & 3)) * 8));
    }
    if (t + 1 < nt) STAGE(t + 1, 1);
    __builtin_amdgcn_s_barrier();
    asm volatile("s_waitcnt lgkmcnt(0)" ::: "memory");
    __builtin_amdgcn_sched_barrier(0);
    __builtin_amdgcn_s_setprio(1);
#pragma unroll
    for (int mf = 0; mf < 4; mf++)
#pragma unroll
      for (int nf = 0; nf < 4; nf++)
        acc[4 + mf][nf] = mfma16(af[mf], bf[nf], acc[4 + mf][nf]);
    __builtin_amdgcn_s_setprio(0);
    if (t + 1 < nt) {
      asm volatile("s_waitcnt vmcnt(4)" ::: "memory");
    } else {
      asm volatile("s_waitcnt vmcnt(0)" ::: "memory");
    }
    __builtin_amdgcn_s_barrier();

    // ---- P2: ds B_k1 + A[mq0,k1]; stage t+1.A_k1; MFMA
#pragma unroll
    for (int nf = 0; nf < 4; nf++) {
      const int row = wn * 64 + nf * 16 + lr;
      bf[nf] = *(const short8*)(Bk1 + row * 32 + ((lc ^ ((row >> 1) & 3)) * 8));
    }
#pragma unroll
    for (int mf = 0; mf < 4; mf++) {
      const int row = wm * 128 + mf * 16 + lr;
      af[mf] = *(const short8*)(Ak1 + row * 32 + ((lc ^ ((row >> 1) & 3)) * 8));
    }
    if (t + 1 < nt) STAGE(t + 1, 2);
    __builtin_amdgcn_s_barrier();
    asm volatile("s_waitcnt lgkmcnt(0)" ::: "memory");
    __builtin_amdgcn_sched_barrier(0);
    __builtin_amdgcn_s_setprio(1);
#pragma unroll
    for (int mf = 0; mf < 4; mf++)
#pragma unroll
      for (int nf = 0; nf < 4; nf++)
        acc[mf][nf] = mfma16(af[mf], bf[nf], acc[mf][nf]);
    __builtin_amdgcn_s_setprio(0);
    __builtin_amdgcn_s_barrier();

    // ---- P3: ds A[mq1,k1]; stage t+1.B_k1; MFMA; vmcnt(4) publishes t+1 A_k0/B_k0
#pragma unroll
    for (int mf = 0; mf < 4; mf++) {
      const int row = wm * 128 + 64 + mf * 16 + lr;
      af[mf] = *(const short8*)(Ak1 + row * 32 + ((lc ^ ((row >> 1) & 3)) * 8));
    }
    if (t + 1 < nt) STAGE(t + 1, 3);
    __builtin_amdgcn_s_barrier();
    asm volatile("s_waitcnt lgkmcnt(0)" ::: "memory");
    __builtin_amdgcn_sched_barrier(0);
    __builtin_amdgcn_s_setprio(1);
#pragma unroll
    for (int mf = 0; mf < 4; mf++)
#pragma unroll
      for (int nf = 0; nf < 4; nf++)
        acc[4 + mf][nf] = mfma16(af[mf], bf[nf], acc[4 + mf][nf]);
    __builtin_amdgcn_s_setprio(0);
    if (t + 1 < nt) {
      asm volatile("s_waitcnt vmcnt(4)" ::: "memory");
    }
    __builtin_amdgcn_s_barrier();
  }

#pragma unroll
  for (int mfp = 0; mfp < 8; mfp++) {
#pragma unroll
    for (int nf = 0; nf < 4; nf++) {
      const int row = bm * 256 + wm * 128 + mfp * 16 + lc * 4;
      const int col = bn * 256 + wn * 64 + nf * 16 + lr;
#pragma unroll
      for (int r = 0; r < 4; r++)
        store_out(C, (size_t)(row + r) * N + col, acc[mfp][nf][r]);
    }
  }
}

// ---------------- flash attention (causal GQA) — R9 config (best: 76us) ----------------
__global__ __launch_bounds__(256, 2) void attn_k(const ushort_t* __restrict__ Qb,
                                                 const ushort_t* __restrict__ Kb,
                                                 const ushort_t* __restrict__ Vf,
                                                 ushort_t* __restrict__ Yb) {
  __shared__ __attribute__((aligned(16))) ushort_t Ks[2][64 * 128];  // 32 KB
  const int tid = threadIdx.x;
  const int lane = tid & 63;
  const int w = tid >> 6;
  const int lr = lane & 15, lc = lane >> 4;
  const int gy = blockIdx.y;
  const int h = gy;
  const int b = blockIdx.z;
  const int kh = h >> 2;
  const int qc = b ? (15 - ((blockIdx.x + gy) & 15)) : ((blockIdx.x + gy) & 15);
  const int q0w = qc * 128 + w * 32;

  const ushort_t* Qp = Qb + (size_t)(b * 16 + h) * T_ * D_;
  const ushort_t* Kp = Kb + (size_t)(b * 4 + kh) * T_ * D_;
  const ushort_t* Vfb = Vf + (size_t)(b * 4 + kh) * 262144;

  const int st_row = tid >> 4;
  const int st_slot = tid & 15;

  short8 qf[2][4];
#pragma unroll
  for (int f = 0; f < 2; f++)
#pragma unroll
    for (int c = 0; c < 4; c++)
      qf[f][c] = *(const short8*)(Qp + (size_t)(q0w + f * 16 + lr) * D_ + c * 32 + lc * 8);

  f32x4 o[2][8];
#pragma unroll
  for (int f = 0; f < 2; f++)
#pragma unroll
    for (int n = 0; n < 8; n++) o[f][n] = (f32x4)(0.0f);
  float m[2] = {-1e30f, -1e30f}, l[2] = {0.0f, 0.0f};

  const int nt = 2 * qc + 2;

#pragma unroll
  for (int i = 0; i < 4; i++) {
    int row = i * 16 + st_row;
    async16(Kp + (size_t)row * D_ + (((st_slot - row) & 15) * 8),
            &Ks[0][0] + row * 128 + st_slot * 8);
  }

#pragma unroll 1
  for (int ti = 0; ti < nt; ti++) {
    __syncthreads();
    const int kv0 = ti * 64;
    if (ti + 1 < nt) {
      const ushort_t* Kn = Kp + (size_t)(kv0 + 64) * D_;
      ushort_t* dst = &Ks[(ti + 1) & 1][0];
#pragma unroll
      for (int i = 0; i < 4; i++) {
        int row = i * 16 + st_row;
        async16(Kn + (size_t)row * D_ + (((st_slot - row) & 15) * 8),
                dst + row * 128 + st_slot * 8);
      }
    }
    if (kv0 > q0w + 31) continue;
    const ushort_t* Kl = &Ks[ti & 1][0];
    const ushort_t* Vt0 = Vfb + (size_t)(ti * 2) * 4096;
    short8 vr0[8];
#pragma unroll
    for (int n = 0; n < 8; n++)
      vr0[n] = *(const short8*)(Vt0 + n * 512 + lane * 8);
    f32x4 s[2][4];
#pragma unroll
    for (int f = 0; f < 2; f++)
#pragma unroll
      for (int kj = 0; kj < 4; kj++) s[f][kj] = (f32x4)(0.0f);
    __builtin_amdgcn_s_setprio(1);
#pragma unroll
    for (int c = 0; c < 4; c++) {
      short8 kf[4];
#pragma unroll
      for (int kj = 0; kj < 4; kj++)
        kf[kj] = *(const short8*)(Kl + (kj * 16 + lr) * 128 + (((c * 4 + lc + lr) & 15) * 8));
#pragma unroll
      for (int f = 0; f < 2; f++)
#pragma unroll
        for (int kj = 0; kj < 4; kj++)
          s[f][kj] = mfma16(kf[kj], qf[f][c], s[f][kj]);
    }
    __builtin_amdgcn_s_setprio(0);
    const ushort_t* Vt1 = Vfb + (size_t)(ti * 2 + 1) * 4096;
    short8 vr1[8];
#pragma unroll
    for (int n = 0; n < 8; n++)
      vr1[n] = *(const short8*)(Vt1 + n * 512 + lane * 8);
    const bool maskt = (kv0 + 63 > q0w);
    union { unsigned u[4]; short8 v; } pa0[2], pa1[2];
#pragma unroll
    for (int f = 0; f < 2; f++) {
      const int q = q0w + f * 16 + lr;
      float pv[16];
      float mx = -1e30f;
      if (maskt) {
#pragma unroll
        for (int kj = 0; kj < 4; kj++)
#pragma unroll
          for (int r = 0; r < 4; r++) {
            float a = s[f][kj][r];
            if (kv0 + kj * 16 + lc * 4 + r > q) a = -1e30f;
            pv[kj * 4 + r] = a;
            mx = fmaxf(mx, a);
          }
      } else {
#pragma unroll
        for (int kj = 0; kj < 4; kj++)
#pragma unroll
          for (int r = 0; r < 4; r++) {
            float a = s[f][kj][r];
            pv[kj * 4 + r] = a;
            mx = fmaxf(mx, a);
          }
      }
      mx = fmaxf(mx, __shfl_xor(mx, 16));
      mx = fmaxf(mx, __shfl_xor(mx, 32));
      const bool need = __any(mx > m[f] + 8.0f);
      const float mn = need ? fmaxf(m[f], mx) : m[f];
      float rs = 0.0f;
#pragma unroll
      for (int i = 0; i < 16; i++) {
        pv[i] = exp2f(pv[i] - mn);
        rs += pv[i];
      }
      rs += __shfl_xor(rs, 16);
      rs += __shfl_xor(rs, 32);
#pragma unroll
      for (int kj = 0; kj < 2; kj++) {
        pa0[f].u[kj * 2] = cvtpk(pv[kj * 4], pv[kj * 4 + 1]);
        pa0[f].u[kj * 2 + 1] = cvtpk(pv[kj * 4 + 2], pv[kj * 4 + 3]);
        pa1[f].u[kj * 2] = cvtpk(pv[8 + kj * 4], pv[8 + kj * 4 + 1]);
        pa1[f].u[kj * 2 + 1] = cvtpk(pv[8 + kj * 4 + 2], pv[8 + kj * 4 + 3]);
      }
      if (need) {
        float al = exp2f(m[f] - mn);
        m[f] = mn;
        l[f] = l[f] * al + rs;
        float alT[4];
#pragma unroll
        for (int r = 0; r < 4; r++)
          alT[r] = __shfl(al, (lane & 48) | (lc * 4 + r));
#pragma unroll
        for (int n = 0; n < 8; n++)
#pragma unroll
          for (int r = 0; r < 4; r++) o[f][n][r] *= alT[r];
      } else {
        l[f] += rs;
      }
    }
    __builtin_amdgcn_s_setprio(1);
#pragma unroll
    for (int n = 0; n < 8; n++) {
      o[0][n] = mfma16(pa0[0].v, vr0[n], o[0][n]);
      o[1][n] = mfma16(pa0[1].v, vr0[n], o[1][n]);
    }
#pragma unroll
    for (int n = 0; n < 8; n++) {
      o[0][n] = mfma16(pa1[0].v, vr1[n], o[0][n]);
      o[1][n] = mfma16(pa1[1].v, vr1[n], o[1][n]);
    }
    __builtin_amdgcn_s_setprio(0);
  }
#pragma unroll
  for (int f = 0; f < 2; f++) {
    float inv = 1.0f / l[f];
    float invT[4];
#pragma unroll
    for (int r = 0; r < 4; r++)
      invT[r] = __shfl(inv, (lane & 48) | (lc * 4 + r));
#pragma unroll
    for (int n = 0; n < 8; n++)
#pragma unroll
      for (int r = 0; r < 4; r++) {
        int qo = q0w + f * 16 + lc * 4 + r;
        int d = n * 16 + lr;
        Yb[(size_t)(b * T_ + qo) * 2048 + h * 128 + d] = f2b(o[f][n][r] * invT[r]);
      }
  }
}

// ---------------- launch ----------------

extern "C" void kernel_launch(void* const* d_in, const int* in_sizes, int n_in,
                              void* d_out, int out_size, void* d_ws, size_t ws_size,
                              hipStream_t stream) {
  (void)in_sizes; (void)n_in; (void)out_size; (void)ws_size;
  const float* x = (const float*)d_in[0];
  const float* wq = (const float*)d_in[1];
  const float* wkv = (const float*)d_in[2];
  const float* wproj = (const float*)d_in[3];
  const float* omega = (const float*)d_in[4];
  float* out = (float*)d_out;
  char* ws = (char*)d_ws;

  ushort_t* xb     = (ushort_t*)(ws + 0);          // 4096x2048 bf16 = 16.8MB
  ushort_t* wqkvT  = (ushort_t*)(ws + 16777216);   // [3072][2048] bf16 (wqT then wkvT)
  ushort_t* wkvT   = (ushort_t*)(ws + 25165824);   // tail of wqkvT
  ushort_t* wprojT = (ushort_t*)(ws + 29360128);   // 2048x2048 bf16
  ushort_t* QKVraw = (ushort_t*)(ws + 37748736);   // 4096x3072 bf16 = 25.2MB
  ushort_t* Qb     = (ushort_t*)(ws + 62914560);   // [b][h][t][d] bf16
  ushort_t* Kb     = (ushort_t*)(ws + 79691776);   // [b][kh][t][d] bf16
  ushort_t* Vf     = (ushort_t*)(ws + 83886080);   // V fragment-packed, 4MB
  ushort_t* Yb     = (ushort_t*)(ws + 88080384);   // 4096x2048 bf16
  float2*   tab    = (float2*)(ws + 104857600);    // 2048x64 float2 = 1MB

  convert_f32_bf16<<<8192, 256, 0, stream>>>(x, xb, 2097152);
  transpose_to_bf16<<<dim3(64, 64), dim3(32, 8), 0, stream>>>(wq, wqkvT, 2048, 2048);
  transpose_to_bf16<<<dim3(32, 64), dim3(32, 8), 0, stream>>>(wkv, wkvT, 2048, 1024);
  transpose_to_bf16<<<dim3(64, 64), dim3(32, 8), 0, stream>>>(wproj, wprojT, 2048, 2048);
  rope_tab_k<<<512, 256, 0, stream>>>(omega, tab);

  // merged QKV projection via 256^2 8-phase (m201 order): [4096,2048]@[3072,2048]^T
  gemm256<<<192, 512, 0, stream>>>(xb, wqkvT, QKVraw, 4096, 3072, 2048);

  rope_q_k<<<16384, 256, 0, stream>>>(QKVraw, tab, Qb);
  rope_k_k<<<4096, 256, 0, stream>>>(QKVraw, tab, Kb);
  v_frag_k<<<1024, 256, 0, stream>>>(QKVraw, Vf);

  attn_k<<<dim3(16, 16, 2), 256, 0, stream>>>(Qb, Kb, Vf, Yb);

  gemm_bt<<<dim3(16, 32), 256, 0, stream>>>(Yb, wprojT, out, 4096, 2048, 2048);
}

// Round 13
// 216.229 us; speedup vs baseline: 1.1174x; 1.0233x over previous
//
#include <hip/hip_runtime.h>
#include <hip/hip_bf16.h>

#define B_ 2
#define T_ 2048
#define C_ 2048
#define H_ 16
#define KH_ 4
#define D_ 128

typedef unsigned short ushort_t;
typedef __attribute__((ext_vector_type(8))) short short8;
typedef __attribute__((ext_vector_type(4))) float f32x4;

#define RSQRT_D 0.08838834764831845f
#define L2E 1.4426950408889634f
// Q pre-scale: 1/sqrt(D) * log2(e)  ->  QK^T lands in log2 units, softmax is pure exp2
#define QSCALE (0.08838834764831845f * 1.4426950408889634f)

__device__ __forceinline__ ushort_t f2b(float f) {
  union { float f; unsigned u; } v; v.f = f;
  unsigned r = v.u + 0x7fffu + ((v.u >> 16) & 1u);
  return (ushort_t)(r >> 16);
}
__device__ __forceinline__ float b2f(ushort_t u) {
  union { unsigned u; float f; } v; v.u = ((unsigned)u) << 16;
  return v.f;
}

__device__ __forceinline__ f32x4 mfma16(short8 a, short8 b, f32x4 c) {
  return __builtin_amdgcn_mfma_f32_16x16x32_bf16(a, b, c, 0, 0, 0);
}

__device__ __forceinline__ void async16(const void* g, void* l) {
  __builtin_amdgcn_global_load_lds(
      (const __attribute__((address_space(1))) void*)g,
      (__attribute__((address_space(3))) void*)l, 16, 0, 0);
}

// packed f32x2 -> bf16x2 (RTNE); dst.lo = bf16(lo), dst.hi = bf16(hi)
__device__ __forceinline__ unsigned cvtpk(float lo, float hi) {
  unsigned r;
  asm volatile("v_cvt_pk_bf16_f32 %0, %1, %2" : "=v"(r) : "v"(lo), "v"(hi));
  return r;
}

// ---------------- small prep kernels ----------------

__global__ void convert_f32_bf16(const float* __restrict__ in, ushort_t* __restrict__ out, int n4) {
  int i = blockIdx.x * blockDim.x + threadIdx.x;
  if (i >= n4) return;
  float4 v = ((const float4*)in)[i];
  ushort4 o;
  o.x = f2b(v.x); o.y = f2b(v.y); o.z = f2b(v.z); o.w = f2b(v.w);
  ((ushort4*)out)[i] = o;
}

// out[c][r] = bf16(in[r][c]);  in: R x C f32, out: C x R bf16
__global__ void transpose_to_bf16(const float* __restrict__ in, ushort_t* __restrict__ out, int R, int C) {
  __shared__ float tile[32][33];
  int c0 = blockIdx.x * 32, r0 = blockIdx.y * 32;
  int tx = threadIdx.x, ty = threadIdx.y;
#pragma unroll
  for (int i = 0; i < 4; i++) {
    int r = ty + i * 8;
    tile[r][tx] = in[(size_t)(r0 + r) * C + c0 + tx];
  }
  __syncthreads();
#pragma unroll
  for (int i = 0; i < 4; i++) {
    int r = ty + i * 8;
    out[(size_t)(c0 + r) * R + r0 + tx] = f2b(tile[tx][r]);
  }
}

// cos/sin table: tab[t*64+d] = (cos(t*omega[d]), sin(t*omega[d]))
__global__ void rope_tab_k(const float* __restrict__ omega, float2* __restrict__ tab) {
  int idx = blockIdx.x * blockDim.x + threadIdx.x;  // 2048*64
  int d = idx & 63;
  int t = idx >> 6;
  float ang = (float)t * omega[d];
  tab[idx] = make_float2(cosf(ang), sinf(ang));
}

// QKVraw [b*T+t][3072]: cols 0..2047 = q -> rope (pre-scaled by QSCALE)
// vectorized x4: thread handles d = d4..d4+3 (and +64 pair)
__global__ void rope_q_k(const ushort_t* __restrict__ QKVraw, const float2* __restrict__ tab,
                         ushort_t* __restrict__ Qb) {
  int idx = blockIdx.x * blockDim.x + threadIdx.x;  // B*T*H*16 = 1048576
  int d4 = (idx & 15) * 4;
  int h = (idx >> 4) & 15;
  int t = (idx >> 8) & 2047;
  int b = idx >> 19;
  size_t in_off = (size_t)(b * 2048 + t) * 3072 + h * 128 + d4;
  ushort4 x1 = *(const ushort4*)(QKVraw + in_off);
  ushort4 x2 = *(const ushort4*)(QKVraw + in_off + 64);
  float4 csA = *(const float4*)(&tab[t * 64 + d4]);      // c0 s0 c1 s1
  float4 csB = *(const float4*)(&tab[t * 64 + d4 + 2]);  // c2 s2 c3 s3
  ushort4 o1, o2;
  o1.x = f2b((b2f(x1.x) * csA.x - b2f(x2.x) * csA.y) * QSCALE);
  o2.x = f2b((b2f(x1.x) * csA.y + b2f(x2.x) * csA.x) * QSCALE);
  o1.y = f2b((b2f(x1.y) * csA.z - b2f(x2.y) * csA.w) * QSCALE);
  o2.y = f2b((b2f(x1.y) * csA.w + b2f(x2.y) * csA.z) * QSCALE);
  o1.z = f2b((b2f(x1.z) * csB.x - b2f(x2.z) * csB.y) * QSCALE);
  o2.z = f2b((b2f(x1.z) * csB.y + b2f(x2.z) * csB.x) * QSCALE);
  o1.w = f2b((b2f(x1.w) * csB.z - b2f(x2.w) * csB.w) * QSCALE);
  o2.w = f2b((b2f(x1.w) * csB.w + b2f(x2.w) * csB.z) * QSCALE);
  size_t out_off = ((size_t)(b * 16 + h) * 2048 + t) * 128 + d4;
  *(ushort4*)(Qb + out_off) = o1;
  *(ushort4*)(Qb + out_off + 64) = o2;
}

// QKVraw cols 2048..2559 = k -> rope -> Kb [(b*4+kh)*T + t][d], vectorized x4
__global__ void rope_k_k(const ushort_t* __restrict__ QKVraw, const float2* __restrict__ tab,
                         ushort_t* __restrict__ Kb) {
  int idx = blockIdx.x * blockDim.x + threadIdx.x;  // B*T*KH*16 = 262144
  int d4 = (idx & 15) * 4;
  int kh = (idx >> 4) & 3;
  int t = (idx >> 6) & 2047;
  int b = idx >> 17;
  size_t in_off = (size_t)(b * 2048 + t) * 3072 + 2048 + kh * 128 + d4;
  ushort4 x1 = *(const ushort4*)(QKVraw + in_off);
  ushort4 x2 = *(const ushort4*)(QKVraw + in_off + 64);
  float4 csA = *(const float4*)(&tab[t * 64 + d4]);
  float4 csB = *(const float4*)(&tab[t * 64 + d4 + 2]);
  ushort4 o1, o2;
  o1.x = f2b(b2f(x1.x) * csA.x - b2f(x2.x) * csA.y);
  o2.x = f2b(b2f(x1.x) * csA.y + b2f(x2.x) * csA.x);
  o1.y = f2b(b2f(x1.y) * csA.z - b2f(x2.y) * csA.w);
  o2.y = f2b(b2f(x1.y) * csA.w + b2f(x2.y) * csA.z);
  o1.z = f2b(b2f(x1.z) * csB.x - b2f(x2.z) * csB.y);
  o2.z = f2b(b2f(x1.z) * csB.y + b2f(x2.z) * csB.x);
  o1.w = f2b(b2f(x1.w) * csB.z - b2f(x2.w) * csB.w);
  o2.w = f2b(b2f(x1.w) * csB.w + b2f(x2.w) * csB.z);
  size_t out_off = ((size_t)(b * 4 + kh) * 2048 + t) * 128 + d4;
  *(ushort4*)(Kb + out_off) = o1;
  *(ushort4*)(Kb + out_off + 64) = o2;
}

// V fragment pre-pack: Vf short8 index = (((z*32+tile)*2+hv)*8+n)*64 + lane
// element j = V[b][t = tile*64 + kl][kh][d = n*16 + (lane&15)]
// kl = (hv*2 + ((j>>1)>>1))*16 + (lane>>4)*4 + 2*((j>>1)&1) + (j&1)
__global__ void v_frag_k(const ushort_t* __restrict__ QKVraw, ushort_t* __restrict__ Vf) {
  int idx = blockIdx.x * blockDim.x + threadIdx.x;  // 262144 short8 units
  int lane = idx & 63;
  int n = (idx >> 6) & 7;
  int hv = (idx >> 9) & 1;
  int tile = (idx >> 10) & 31;
  int z = idx >> 15;  // b*4+kh
  int b = z >> 2, kh = z & 3;
  int lr = lane & 15, lc = lane >> 4;
  int d = n * 16 + lr;
  union { ushort_t u[8]; short8 v; } out;
#pragma unroll
  for (int j = 0; j < 8; j++) {
    int tw = j >> 1, par = j & 1;
    int kl = (hv * 2 + (tw >> 1)) * 16 + lc * 4 + 2 * (tw & 1) + par;
    int t = tile * 64 + kl;
    out.u[j] = QKVraw[(size_t)(b * 2048 + t) * 3072 + 2560 + kh * 128 + d];
  }
  *(short8*)(Vf + (size_t)idx * 8) = out.v;
}

__device__ __forceinline__ void store_out(float* C, size_t idx, float v) { C[idx] = v; }
__device__ __forceinline__ void store_out(ushort_t* C, size_t idx, float v) { C[idx] = f2b(v); }

// ---------------- GEMM 128x128 (proj): 2-phase dbuf, counted vmcnt ----------------

template <typename OUT_T>
__global__ __launch_bounds__(256) void gemm_bt(const ushort_t* __restrict__ A,
                                               const ushort_t* __restrict__ Bt,
                                               OUT_T* __restrict__ C,
                                               int M, int N, int K) {
  __shared__ __attribute__((aligned(16))) ushort_t As[2][128 * 32];
  __shared__ __attribute__((aligned(16))) ushort_t Bs[2][128 * 32];
  const int tid = threadIdx.x;
  const int lane = tid & 63;
  const int w = tid >> 6;
  const int bm = blockIdx.y, bn = blockIdx.x;
  const int lr = lane & 15, lc = lane >> 4;
  const int wr = (w >> 1) * 64, wc = (w & 1) * 64;
  const ushort_t* Ab = A + (size_t)bm * 128 * K;
  const ushort_t* Bb = Bt + (size_t)bn * 128 * K;
  const int srow = tid >> 2;
  const int scol = (tid & 3) * 8;
  f32x4 acc[4][4];
#pragma unroll
  for (int i = 0; i < 4; i++)
#pragma unroll
    for (int j = 0; j < 4; j++) acc[i][j] = (f32x4)(0.0f);

  async16(Ab + (size_t)srow * K + scol, &As[0][0] + srow * 32 + scol);
  async16(Ab + (size_t)(srow + 64) * K + scol, &As[0][0] + (srow + 64) * 32 + scol);
  async16(Bb + (size_t)srow * K + scol, &Bs[0][0] + srow * 32 + scol);
  async16(Bb + (size_t)(srow + 64) * K + scol, &Bs[0][0] + (srow + 64) * 32 + scol);

  const int nt = K >> 5;
#pragma unroll 2
  for (int t = 0; t < nt - 1; t++) {
    const int cur = t & 1;
    {
      const int k1 = (t + 1) << 5;
      ushort_t* Ad = &As[cur ^ 1][0];
      ushort_t* Bd = &Bs[cur ^ 1][0];
      async16(Ab + (size_t)srow * K + k1 + scol, Ad + srow * 32 + scol);
      async16(Ab + (size_t)(srow + 64) * K + k1 + scol, Ad + (srow + 64) * 32 + scol);
      async16(Bb + (size_t)srow * K + k1 + scol, Bd + srow * 32 + scol);
      async16(Bb + (size_t)(srow + 64) * K + k1 + scol, Bd + (srow + 64) * 32 + scol);
    }
    asm volatile("s_waitcnt vmcnt(4)" ::: "memory");
    __builtin_amdgcn_s_barrier();
    __builtin_amdgcn_sched_barrier(0);
    const ushort_t* Al = &As[cur][0];
    const ushort_t* Bl = &Bs[cur][0];
    short8 af[4], bf[4];
#pragma unroll
    for (int mi = 0; mi < 4; mi++)
      af[mi] = *(const short8*)(Al + (wr + mi * 16 + lr) * 32 + lc * 8);
#pragma unroll
    for (int ni = 0; ni < 4; ni++)
      bf[ni] = *(const short8*)(Bl + (wc + ni * 16 + lr) * 32 + lc * 8);
#pragma unroll
    for (int mi = 0; mi < 4; mi++)
#pragma unroll
      for (int ni = 0; ni < 4; ni++)
        acc[mi][ni] = mfma16(af[mi], bf[ni], acc[mi][ni]);
    asm volatile("" ::: "memory");
    __builtin_amdgcn_s_barrier();
    asm volatile("" ::: "memory");
  }
  {
    const int cur = (nt - 1) & 1;
    asm volatile("s_waitcnt vmcnt(0)" ::: "memory");
    __builtin_amdgcn_s_barrier();
    __builtin_amdgcn_sched_barrier(0);
    const ushort_t* Al = &As[cur][0];
    const ushort_t* Bl = &Bs[cur][0];
    short8 af[4], bf[4];
#pragma unroll
    for (int mi = 0; mi < 4; mi++)
      af[mi] = *(const short8*)(Al + (wr + mi * 16 + lr) * 32 + lc * 8);
#pragma unroll
    for (int ni = 0; ni < 4; ni++)
      bf[ni] = *(const short8*)(Bl + (wc + ni * 16 + lr) * 32 + lc * 8);
#pragma unroll
    for (int mi = 0; mi < 4; mi++)
#pragma unroll
      for (int ni = 0; ni < 4; ni++)
        acc[mi][ni] = mfma16(af[mi], bf[ni], acc[mi][ni]);
  }
#pragma unroll
  for (int mi = 0; mi < 4; mi++) {
#pragma unroll
    for (int ni = 0; ni < 4; ni++) {
      int row = bm * 128 + wr + mi * 16 + lc * 4;
      int col = bn * 128 + wc + ni * 16 + lr;
#pragma unroll
      for (int r = 0; r < 4; r++)
        store_out(C, (size_t)(row + r) * N + col, acc[mi][ni][r]);
    }
  }
}

// ---------------- GEMM 256x192 8-phase (QKV) — 100% CU fill ----------------
// BM=256, BN=192, BK=64 as k0/k1 halves. 512 thr = 8 waves (2M x 4N);
// per-wave C = 128x48 (acc[8][3]). Grid 16x16 = 256 blocks = 1/CU exact.
// LDS: A 2x2x16KB + B 2x2x12KB + 1KB scratch = 113.5KB -> 1 block/CU.
// STAGE is ALWAYS 2 async16/thread (B's 768 units: load0 = all threads,
// load1 = threads<256 real, threads>=256 -> scratch) so the counted-vmcnt
// constants are identical to the proven R11/R12 schedule.
template <typename OUT_T>
__global__ __launch_bounds__(512, 1) void gemm256(const ushort_t* __restrict__ A,
                                                  const ushort_t* __restrict__ Bt,
                                                  OUT_T* __restrict__ C,
                                                  int M, int N, int K) {
  __shared__ __attribute__((aligned(16))) ushort_t As[2][2][8192];
  __shared__ __attribute__((aligned(16))) ushort_t Bs[2][2][6144];
  __shared__ __attribute__((aligned(16))) ushort_t Scr[512];
  const int tid = threadIdx.x;
  const int lane = tid & 63;
  const int w = tid >> 6;          // 0..7
  const int lr = lane & 15, lc = lane >> 4;
  const int wm = w >> 2, wn = w & 3;
  // XCD-aware bijective swizzle over 1D grid (256 % 8 == 0)
  const int nwg = gridDim.x;
  const int cpx = nwg >> 3;
  const int swz = (blockIdx.x & 7) * cpx + (blockIdx.x >> 3);
  const int bnc = N / 192;
  const int bm = swz / bnc, bn = swz % bnc;
  const ushort_t* Ab = A + (size_t)bm * 256 * K;
  const ushort_t* Bb = Bt + (size_t)bn * 192 * K;

  f32x4 acc[8][3];
#pragma unroll
  for (int i = 0; i < 8; i++)
#pragma unroll
    for (int j = 0; j < 3; j++) acc[i][j] = (f32x4)(0.0f);

  auto STAGE = [&](int kt, int hid) {
    const int buf = kt & 1;
    const int kk = hid >> 1;
    const int kbase = kt * 64 + kk * 32;
    if (!(hid & 1)) {
      // A half: 1024 units; u0 = tid, u1 = 512 + tid
      ushort_t* db = &As[buf][kk][0];
      {
        const int u = tid, row = u >> 2, c = u & 3;
        const int lch = c ^ ((row >> 1) & 3);
        async16(Ab + (size_t)row * K + kbase + lch * 8, db + u * 8);
      }
      {
        const int u = 512 + tid, row = u >> 2, c = u & 3;
        const int lch = c ^ ((row >> 1) & 3);
        async16(Ab + (size_t)row * K + kbase + lch * 8, db + u * 8);
      }
    } else {
      // B half: 768 units; u0 = tid (all), u1 = 512+tid for tid<256, else scratch
      ushort_t* db = &Bs[buf][kk][0];
      {
        const int u = tid, row = u >> 2, c = u & 3;
        const int lch = c ^ ((row >> 1) & 3);
        async16(Bb + (size_t)row * K + kbase + lch * 8, db + u * 8);
      }
      if (tid < 256) {
        const int u = 512 + tid, row = u >> 2, c = u & 3;
        const int lch = c ^ ((row >> 1) & 3);
        async16(Bb + (size_t)row * K + kbase + lch * 8, db + u * 8);
      } else {
        // dummy keeps per-wave vmcnt counts uniform; Scr never read
        async16(Bb + (size_t)(tid - 256) * 8, &Scr[0]);
      }
    }
  };

  const int nt = K >> 6;
  // prologue: stage tile0 fully; publish A_k0/B_k0 (keep A_k1/B_k1 in flight)
  STAGE(0, 0); STAGE(0, 1); STAGE(0, 2); STAGE(0, 3);
  asm volatile("s_waitcnt vmcnt(4)" ::: "memory");
  __builtin_amdgcn_s_barrier();

#pragma unroll 1
  for (int t = 0; t < nt; ++t) {
    const int buf = t & 1;
    const ushort_t* Ak0 = &As[buf][0][0];
    const ushort_t* Ak1 = &As[buf][1][0];
    const ushort_t* Bk0 = &Bs[buf][0][0];
    const ushort_t* Bk1 = &Bs[buf][1][0];
    short8 af[4], bf[3];

    // ---- P0: ds B_k0 + A[mq0,k0]; stage t+1.A_k0
#pragma unroll
    for (int nf = 0; nf < 3; nf++) {
      const int row = wn * 48 + nf * 16 + lr;
      bf[nf] = *(const short8*)(Bk0 + row * 32 + ((lc ^ ((row >> 1) & 3)) * 8));
    }
#pragma unroll
    for (int mf = 0; mf < 4; mf++) {
      const int row = wm * 128 + mf * 16 + lr;
      af[mf] = *(const short8*)(Ak0 + row * 32 + ((lc ^ ((row >> 1) & 3)) * 8));
    }
    if (t + 1 < nt) STAGE(t + 1, 0);
    __builtin_amdgcn_s_barrier();
    asm volatile("s_waitcnt lgkmcnt(0)" ::: "memory");
    __builtin_amdgcn_sched_barrier(0);
    __builtin_amdgcn_s_setprio(1);
#pragma unroll
    for (int mf = 0; mf < 4; mf++)
#pragma unroll
      for (int nf = 0; nf < 3; nf++)
        acc[mf][nf] = mfma16(af[mf], bf[nf], acc[mf][nf]);
    __builtin_amdgcn_s_setprio(0);
    __builtin_amdgcn_s_barrier();

    // ---- P1: ds A[mq1,k0]; stage t+1.B_k0; MFMA; vmcnt publishes A_k1/B_k1
#pragma unroll
    for (int mf = 0; mf < 4; mf++) {
      const int row = wm * 128 + 64 + mf * 16 + lr;
      af[mf] = *(const short8*)(Ak0 + row * 32 + ((lc ^ ((row >> 1) & 3)) * 8));
    }
    if (t + 1 < nt) STAGE(t + 1, 1);
    __builtin_amdgcn_s_barrier();
    asm volatile("s_waitcnt lgkmcnt(0)" ::: "memory");
    __builtin_amdgcn_sched_barrier(0);
    __builtin_amdgcn_s_setprio(1);
#pragma unroll
    for (int mf = 0; mf < 4; mf++)
#pragma unroll
      for (int nf = 0; nf < 3; nf++)
        acc[4 + mf][nf] = mfma16(af[mf], bf[nf], acc[4 + mf][nf]);
    __builtin_amdgcn_s_setprio(0);
    if (t + 1 < nt) {
      asm volatile("s_waitcnt vmcnt(4)" ::: "memory");
    } else {
      asm volatile("s_waitcnt vmcnt(0)" ::: "memory");
    }
    __builtin_amdgcn_s_barrier();

    // ---- P2: ds B_k1 + A[mq0,k1]; stage t+1.A_k1; MFMA
#pragma unroll
    for (int nf = 0; nf < 3; nf++) {
      const int row = wn * 48 + nf * 16 + lr;
      bf[nf] = *(const short8*)(Bk1 + row * 32 + ((lc ^ ((row >> 1) & 3)) * 8));
    }
#pragma unroll
    for (int mf = 0; mf < 4; mf++) {
      const int row = wm * 128 + mf * 16 + lr;
      af[mf] = *(const short8*)(Ak1 + row * 32 + ((lc ^ ((row >> 1) & 3)) * 8));
    }
    if (t + 1 < nt) STAGE(t + 1, 2);
    __builtin_amdgcn_s_barrier();
    asm volatile("s_waitcnt lgkmcnt(0)" ::: "memory");
    __builtin_amdgcn_sched_barrier(0);
    __builtin_amdgcn_s_setprio(1);
#pragma unroll
    for (int mf = 0; mf < 4; mf++)
#pragma unroll
      for (int nf = 0; nf < 3; nf++)
        acc[mf][nf] = mfma16(af[mf], bf[nf], acc[mf][nf]);
    __builtin_amdgcn_s_setprio(0);
    __builtin_amdgcn_s_barrier();

    // ---- P3: ds A[mq1,k1]; stage t+1.B_k1; MFMA; vmcnt publishes t+1 A_k0/B_k0
#pragma unroll
    for (int mf = 0; mf < 4; mf++) {
      const int row = wm * 128 + 64 + mf * 16 + lr;
      af[mf] = *(const short8*)(Ak1 + row * 32 + ((lc ^ ((row >> 1) & 3)) * 8));
    }
    if (t + 1 < nt) STAGE(t + 1, 3);
    __builtin_amdgcn_s_barrier();
    asm volatile("s_waitcnt lgkmcnt(0)" ::: "memory");
    __builtin_amdgcn_sched_barrier(0);
    __builtin_amdgcn_s_setprio(1);
#pragma unroll
    for (int mf = 0; mf < 4; mf++)
#pragma unroll
      for (int nf = 0; nf < 3; nf++)
        acc[4 + mf][nf] = mfma16(af[mf], bf[nf], acc[4 + mf][nf]);
    __builtin_amdgcn_s_setprio(0);
    if (t + 1 < nt) {
      asm volatile("s_waitcnt vmcnt(4)" ::: "memory");
    }
    __builtin_amdgcn_s_barrier();
  }

#pragma unroll
  for (int mfp = 0; mfp < 8; mfp++) {
#pragma unroll
    for (int nf = 0; nf < 3; nf++) {
      const int row = bm * 256 + wm * 128 + mfp * 16 + lc * 4;
      const int col = bn * 192 + wn * 48 + nf * 16 + lr;
#pragma unroll
      for (int r = 0; r < 4; r++)
        store_out(C, (size_t)(row + r) * N + col, acc[mfp][nf][r]);
    }
  }
}

// ---------------- flash attention (causal GQA) — R9 config (best: 76us) ----------------
__global__ __launch_bounds__(256, 2) void attn_k(const ushort_t* __restrict__ Qb,
                                                 const ushort_t* __restrict__ Kb,
                                                 const ushort_t* __restrict__ Vf,
                                                 ushort_t* __restrict__ Yb) {
  __shared__ __attribute__((aligned(16))) ushort_t Ks[2][64 * 128];  // 32 KB
  const int tid = threadIdx.x;
  const int lane = tid & 63;
  const int w = tid >> 6;
  const int lr = lane & 15, lc = lane >> 4;
  const int gy = blockIdx.y;
  const int h = gy;
  const int b = blockIdx.z;
  const int kh = h >> 2;
  const int qc = b ? (15 - ((blockIdx.x + gy) & 15)) : ((blockIdx.x + gy) & 15);
  const int q0w = qc * 128 + w * 32;

  const ushort_t* Qp = Qb + (size_t)(b * 16 + h) * T_ * D_;
  const ushort_t* Kp = Kb + (size_t)(b * 4 + kh) * T_ * D_;
  const ushort_t* Vfb = Vf + (size_t)(b * 4 + kh) * 262144;

  const int st_row = tid >> 4;
  const int st_slot = tid & 15;

  short8 qf[2][4];
#pragma unroll
  for (int f = 0; f < 2; f++)
#pragma unroll
    for (int c = 0; c < 4; c++)
      qf[f][c] = *(const short8*)(Qp + (size_t)(q0w + f * 16 + lr) * D_ + c * 32 + lc * 8);

  f32x4 o[2][8];
#pragma unroll
  for (int f = 0; f < 2; f++)
#pragma unroll
    for (int n = 0; n < 8; n++) o[f][n] = (f32x4)(0.0f);
  float m[2] = {-1e30f, -1e30f}, l[2] = {0.0f, 0.0f};

  const int nt = 2 * qc + 2;

#pragma unroll
  for (int i = 0; i < 4; i++) {
    int row = i * 16 + st_row;
    async16(Kp + (size_t)row * D_ + (((st_slot - row) & 15) * 8),
            &Ks[0][0] + row * 128 + st_slot * 8);
  }

#pragma unroll 1
  for (int ti = 0; ti < nt; ti++) {
    __syncthreads();
    const int kv0 = ti * 64;
    if (ti + 1 < nt) {
      const ushort_t* Kn = Kp + (size_t)(kv0 + 64) * D_;
      ushort_t* dst = &Ks[(ti + 1) & 1][0];
#pragma unroll
      for (int i = 0; i < 4; i++) {
        int row = i * 16 + st_row;
        async16(Kn + (size_t)row * D_ + (((st_slot - row) & 15) * 8),
                dst + row * 128 + st_slot * 8);
      }
    }
    if (kv0 > q0w + 31) continue;
    const ushort_t* Kl = &Ks[ti & 1][0];
    const ushort_t* Vt0 = Vfb + (size_t)(ti * 2) * 4096;
    short8 vr0[8];
#pragma unroll
    for (int n = 0; n < 8; n++)
      vr0[n] = *(const short8*)(Vt0 + n * 512 + lane * 8);
    f32x4 s[2][4];
#pragma unroll
    for (int f = 0; f < 2; f++)
#pragma unroll
      for (int kj = 0; kj < 4; kj++) s[f][kj] = (f32x4)(0.0f);
    __builtin_amdgcn_s_setprio(1);
#pragma unroll
    for (int c = 0; c < 4; c++) {
      short8 kf[4];
#pragma unroll
      for (int kj = 0; kj < 4; kj++)
        kf[kj] = *(const short8*)(Kl + (kj * 16 + lr) * 128 + (((c * 4 + lc + lr) & 15) * 8));
#pragma unroll
      for (int f = 0; f < 2; f++)
#pragma unroll
        for (int kj = 0; kj < 4; kj++)
          s[f][kj] = mfma16(kf[kj], qf[f][c], s[f][kj]);
    }
    __builtin_amdgcn_s_setprio(0);
    const ushort_t* Vt1 = Vfb + (size_t)(ti * 2 + 1) * 4096;
    short8 vr1[8];
#pragma unroll
    for (int n = 0; n < 8; n++)
      vr1[n] = *(const short8*)(Vt1 + n * 512 + lane * 8);
    const bool maskt = (kv0 + 63 > q0w);
    union { unsigned u[4]; short8 v; } pa0[2], pa1[2];
#pragma unroll
    for (int f = 0; f < 2; f++) {
      const int q = q0w + f * 16 + lr;
      float pv[16];
      float mx = -1e30f;
      if (maskt) {
#pragma unroll
        for (int kj = 0; kj < 4; kj++)
#pragma unroll
          for (int r = 0; r < 4; r++) {
            float a = s[f][kj][r];
            if (kv0 + kj * 16 + lc * 4 + r > q) a = -1e30f;
            pv[kj * 4 + r] = a;
            mx = fmaxf(mx, a);
          }
      } else {
#pragma unroll
        for (int kj = 0; kj < 4; kj++)
#pragma unroll
          for (int r = 0; r < 4; r++) {
            float a = s[f][kj][r];
            pv[kj * 4 + r] = a;
            mx = fmaxf(mx, a);
          }
      }
      mx = fmaxf(mx, __shfl_xor(mx, 16));
      mx = fmaxf(mx, __shfl_xor(mx, 32));
      const bool need = __any(mx > m[f] + 8.0f);
      const float mn = need ? fmaxf(m[f], mx) : m[f];
      float rs = 0.0f;
#pragma unroll
      for (int i = 0; i < 16; i++) {
        pv[i] = exp2f(pv[i] - mn);
        rs += pv[i];
      }
      rs += __shfl_xor(rs, 16);
      rs += __shfl_xor(rs, 32);
#pragma unroll
      for (int kj = 0; kj < 2; kj++) {
        pa0[f].u[kj * 2] = cvtpk(pv[kj * 4], pv[kj * 4 + 1]);
        pa0[f].u[kj * 2 + 1] = cvtpk(pv[kj * 4 + 2], pv[kj * 4 + 3]);
        pa1[f].u[kj * 2] = cvtpk(pv[8 + kj * 4], pv[8 + kj * 4 + 1]);
        pa1[f].u[kj * 2 + 1] = cvtpk(pv[8 + kj * 4 + 2], pv[8 + kj * 4 + 3]);
      }
      if (need) {
        float al = exp2f(m[f] - mn);
        m[f] = mn;
        l[f] = l[f] * al + rs;
        float alT[4];
#pragma unroll
        for (int r = 0; r < 4; r++)
          alT[r] = __shfl(al, (lane & 48) | (lc * 4 + r));
#pragma unroll
        for (int n = 0; n < 8; n++)
#pragma unroll
          for (int r = 0; r < 4; r++) o[f][n][r] *= alT[r];
      } else {
        l[f] += rs;
      }
    }
    __builtin_amdgcn_s_setprio(1);
#pragma unroll
    for (int n = 0; n < 8; n++) {
      o[0][n] = mfma16(pa0[0].v, vr0[n], o[0][n]);
      o[1][n] = mfma16(pa0[1].v, vr0[n], o[1][n]);
    }
#pragma unroll
    for (int n = 0; n < 8; n++) {
      o[0][n] = mfma16(pa1[0].v, vr1[n], o[0][n]);
      o[1][n] = mfma16(pa1[1].v, vr1[n], o[1][n]);
    }
    __builtin_amdgcn_s_setprio(0);
  }
#pragma unroll
  for (int f = 0; f < 2; f++) {
    float inv = 1.0f / l[f];
    float invT[4];
#pragma unroll
    for (int r = 0; r < 4; r++)
      invT[r] = __shfl(inv, (lane & 48) | (lc * 4 + r));
#pragma unroll
    for (int n = 0; n < 8; n++)
#pragma unroll
      for (int r = 0; r < 4; r++) {
        int qo = q0w + f * 16 + lc * 4 + r;
        int d = n * 16 + lr;
        Yb[(size_t)(b * T_ + qo) * 2048 + h * 128 + d] = f2b(o[f][n][r] * invT[r]);
      }
  }
}

// ---------------- launch ----------------

extern "C" void kernel_launch(void* const* d_in, const int* in_sizes, int n_in,
                              void* d_out, int out_size, void* d_ws, size_t ws_size,
                              hipStream_t stream) {
  (void)in_sizes; (void)n_in; (void)out_size; (void)ws_size;
  const float* x = (const float*)d_in[0];
  const float* wq = (const float*)d_in[1];
  const float* wkv = (const float*)d_in[2];
  const float* wproj = (const float*)d_in[3];
  const float* omega = (const float*)d_in[4];
  float* out = (float*)d_out;
  char* ws = (char*)d_ws;

  ushort_t* xb     = (ushort_t*)(ws + 0);          // 4096x2048 bf16 = 16.8MB
  ushort_t* wqkvT  = (ushort_t*)(ws + 16777216);   // [3072][2048] bf16 (wqT then wkvT)
  ushort_t* wkvT   = (ushort_t*)(ws + 25165824);   // tail of wqkvT
  ushort_t* wprojT = (ushort_t*)(ws + 29360128);   // 2048x2048 bf16
  ushort_t* QKVraw = (ushort_t*)(ws + 37748736);   // 4096x3072 bf16 = 25.2MB
  ushort_t* Qb     = (ushort_t*)(ws + 62914560);   // [b][h][t][d] bf16
  ushort_t* Kb     = (ushort_t*)(ws + 79691776);   // [b][kh][t][d] bf16
  ushort_t* Vf     = (ushort_t*)(ws + 83886080);   // V fragment-packed, 4MB
  ushort_t* Yb     = (ushort_t*)(ws + 88080384);   // 4096x2048 bf16
  float2*   tab    = (float2*)(ws + 104857600);    // 2048x64 float2 = 1MB

  convert_f32_bf16<<<8192, 256, 0, stream>>>(x, xb, 2097152);
  transpose_to_bf16<<<dim3(64, 64), dim3(32, 8), 0, stream>>>(wq, wqkvT, 2048, 2048);
  transpose_to_bf16<<<dim3(32, 64), dim3(32, 8), 0, stream>>>(wkv, wkvT, 2048, 1024);
  transpose_to_bf16<<<dim3(64, 64), dim3(32, 8), 0, stream>>>(wproj, wprojT, 2048, 2048);
  rope_tab_k<<<512, 256, 0, stream>>>(omega, tab);

  // merged QKV projection via 256x192 8-phase (256 blocks = 100% CU fill)
  gemm256<<<256, 512, 0, stream>>>(xb, wqkvT, QKVraw, 4096, 3072, 2048);

  rope_q_k<<<4096, 256, 0, stream>>>(QKVraw, tab, Qb);
  rope_k_k<<<1024, 256, 0, stream>>>(QKVraw, tab, Kb);
  v_frag_k<<<1024, 256, 0, stream>>>(QKVraw, Vf);

  attn_k<<<dim3(16, 16, 2), 256, 0, stream>>>(Qb, Kb, Vf, Yb);

  gemm_bt<<<dim3(16, 32), 256, 0, stream>>>(Yb, wprojT, out, 4096, 2048, 2048);
}